// Round 1
// baseline (451.570 us; speedup 1.0000x reference)
//
#include <hip/hip_runtime.h>
#include <string.h>

// Conformer encoder layer, MI355X gfx950 — ROUND 11.
// R10: 444 us. gemm_nt128 ~64us each: MfmaUtil 5%, VALUBusy 18%, HBM 7%,
// occupancy 21% -> latency-bound (every BK=32 step exposes full glds latency
// via __syncthreads vmcnt(0) drain; grid-limited 2 blocks/CU, nothing to
// overlap with).
// Changes: gemm_nt + gemm_nt128 -> double-buffered LDS + 2-deep prefetch +
// counted s_waitcnt vmcnt(4) + raw s_barrier (T3/T4 pattern). Prefetch of
// tile t+2 issued right after the barrier retiring tile t's reads; main loop
// never drains vmcnt to 0. gemm_nt A-stage row-clamped (no divergent glds ->
// uniform per-wave vmcnt count). flash_k unchanged this round.
// T=1024 B=4 E=512 H=8 D=64 DFF=2048 K=31. Workspace: 93 MB.

#define T_ 1024
#define B_ 4
#define E_ 512
#define H_ 8
#define DFF_ 2048
#define KW_ 31

typedef unsigned short u16;
typedef unsigned int u32;
typedef __bf16 bf16x8 __attribute__((ext_vector_type(8)));
typedef float floatx4 __attribute__((ext_vector_type(4)));

__device__ __forceinline__ float b2f(u16 u) {
    return __uint_as_float(((u32)u) << 16);
}
__device__ __forceinline__ u16 f2b(float f) {
    u32 i = __float_as_uint(f);
    u32 r = (i + 0x7fffu + ((i >> 16) & 1u)) >> 16;  // RNE, finite inputs only
    return (u16)r;
}

__device__ __forceinline__ void glds16(const u16 *g, u16 *l) {
    __builtin_amdgcn_global_load_lds((const __attribute__((address_space(1))) void *)g,
                                     (__attribute__((address_space(3))) void *)l, 16, 0, 0);
}

// ---------------- diagnostic fill (f32 out) ---------------------------------------
__global__ __launch_bounds__(256) void fill_k(float *out, long long n, float val) {
    long long g = (long long)blockIdx.x * 256 + threadIdx.x;
    if (g < n) out[g] = val;
}

// ---------------- input dtype detect + convert ------------------------------------
__global__ __launch_bounds__(256) void detect_k(const u16 *src16, int *flag) {
    __shared__ int sh[256];
    int tid = threadIdx.x;
    int cnt = 0;
    for (int i = tid; i < 4096; i += 256) {
        u16 x = src16[2 * i];
        int e = (x >> 7) & 0xFF;
        cnt += (e == 0 || (e >= 0x70 && e <= 0x8F)) ? 1 : 0;
    }
    sh[tid] = cnt;
    __syncthreads();
    for (int s = 128; s; s >>= 1) {
        if (tid < s) sh[tid] += sh[tid + s];
        __syncthreads();
    }
    if (tid == 0) *flag = (sh[0] < 2048) ? 1 : 0;  // 1 = f32 inputs, 0 = bf16
}

struct CVT {
    const void *in[24];
    long long pre[25];
};

__global__ __launch_bounds__(256) void convert_k(CVT c, u16 *dst, const int *flag,
                                                 long long total) {
    long long g = (long long)blockIdx.x * 256 + threadIdx.x;
    if (g >= total) return;
    int s = 0;
#pragma unroll
    for (int i = 1; i < 25; i++) s += (g >= c.pre[i]) ? 1 : 0;
    long long l = g - c.pre[s];
    int f = *flag;
    u16 v = f ? f2b(((const float *)c.in[s])[l]) : ((const u16 *)c.in[s])[l];
    dst[g] = v;
}

// ---------------- generic NT GEMM: C(M,N) = A(M,K) @ B(N,K)^T ----------------------
struct GP {
    const u16 *A, *B;
    u16 *C;
    const u16 *bias;
    const void *resin;     // mode 2: residual input (bf16 or f32)
    float *xr;             // mode 2: f32 residual out
    u16 *xb;               // mode 2: bf16 copy out (may be null)
    int M, N, K, lda, ldb, ldc, mode, qcols, resin_f32;
    float qscale;
};

// 64x64 tile, BK=64, glds16 staging w/ XOR swizzle (conflict-free b128 reads).
// R11: double-buffered LDS, 2-deep prefetch, counted vmcnt(4), raw barriers.
// modes: 0 = bf16 store; 1 = DoubleSwish then bf16 store; 2 = residual (f32+bf16)
__global__ __launch_bounds__(256) void gemm_nt(GP p) {
    __shared__ __align__(16) u16 As[2 * 64 * 64];
    __shared__ __align__(16) u16 Bs[2 * 64 * 64];
    const int tid = threadIdx.x;
    const int wv = tid >> 6, ln = tid & 63;
    const int l16 = ln & 15, quad = ln >> 4;
    const int m0 = blockIdx.y * 64, n0 = blockIdx.x * 64;
    floatx4 zero = {0.f, 0.f, 0.f, 0.f};
    floatx4 acc[4];
#pragma unroll
    for (int i = 0; i < 4; i++) acc[i] = zero;

    const int NT = p.K >> 6;  // BK=64; all call-site K are multiples of 64, K>=512

    // stage = 4 glds16 per wave (A x2, B x2). Row-clamped A: no divergence,
    // uniform per-wave vmcnt count. Clamped rows produce dup data in unused
    // output rows (masked at store).
    auto stage = [&](int buf, int t) {
        const int k0 = t << 6;
        const int o = buf << 12;  // 4096 u16 per buffer
#pragma unroll
        for (int ps = 0; ps < 2; ps++) {
            int g = ps * 256 + tid;
            int row = g >> 3;
            int src = ((g & 7) ^ (row & 7)) << 3;
            int ra = m0 + row;
            if (ra > p.M - 1) ra = p.M - 1;
            glds16(p.A + (long long)ra * p.lda + k0 + src, As + o + g * 8);
            glds16(p.B + (long long)(n0 + row) * p.ldb + k0 + src, Bs + o + g * 8);
        }
    };

    stage(0, 0);
    stage(1, 1);
    asm volatile("s_waitcnt vmcnt(4)" ::: "memory");  // buf0's 4 loads done
    __builtin_amdgcn_s_barrier();

    for (int t = 0; t < NT; t++) {
        const int o = (t & 1) << 12;
#pragma unroll
        for (int kk = 0; kk < 2; kk++) {
            const int swz = ((((kk << 2) | quad) ^ (l16 & 7)) << 3);
            bf16x8 af = __builtin_bit_cast(bf16x8,
                *(const uint4 *)&As[o + (((wv << 4) | l16) << 6) + swz]);
#pragma unroll
            for (int nt = 0; nt < 4; nt++) {
                bf16x8 bf = __builtin_bit_cast(bf16x8,
                    *(const uint4 *)&Bs[o + (((nt << 4) | l16) << 6) + swz]);
                acc[nt] = __builtin_amdgcn_mfma_f32_16x16x32_bf16(af, bf, acc[nt], 0, 0, 0);
            }
        }
        if (t + 1 < NT) {
            __builtin_amdgcn_sched_barrier(0);   // reads of buf complete before barrier
            __builtin_amdgcn_s_barrier();        // all waves done reading buf
            if (t + 2 < NT) {
                stage(t & 1, t + 2);             // re-stage retired buffer
                asm volatile("s_waitcnt vmcnt(4)" ::: "memory");  // next buf's loads done
            } else {
                asm volatile("s_waitcnt vmcnt(0)" ::: "memory");  // tail drain
            }
            __builtin_amdgcn_s_barrier();        // next buf visible everywhere
            __builtin_amdgcn_sched_barrier(0);   // no hoisting of next reads above this
        }
    }

#pragma unroll
    for (int nt = 0; nt < 4; nt++) {
#pragma unroll
        for (int r = 0; r < 4; r++) {
            int gr = m0 + (wv << 4) + (quad << 2) + r;
            int gc = n0 + (nt << 4) + l16;
            if (gr >= p.M) continue;
            float y = acc[nt][r];
            if (p.bias) y += b2f(p.bias[gc]);
            if (gc < p.qcols) y *= p.qscale;
            if (p.mode == 0) {
                p.C[(long long)gr * p.ldc + gc] = f2b(y);
            } else if (p.mode == 1) {
                float s = 1.f / (1.f + __expf(1.f - y));  // x*sigmoid(x-1)
                p.C[(long long)gr * p.ldc + gc] = f2b(y * s);
            } else {  // mode 2
                long long idx = (long long)gr * p.ldc + gc;
                float rv = p.resin_f32 ? ((const float *)p.resin)[idx]
                                       : b2f(((const u16 *)p.resin)[idx]);
                float o = rv + y;
                p.xr[idx] = o;
                if (p.xb) p.xb[idx] = f2b(o);
            }
        }
    }
}

// ---------------- 128x128 m97-style GEMM (z=1, M%128==0, N%128==0, K%32==0) --------
// v2: XOR swizzle on 4-granule rows kills the 8-way read conflicts.
// R11: double-buffered LDS, 2-deep prefetch, counted vmcnt(4), raw barriers.
__global__ __launch_bounds__(256) void gemm_nt128(GP p) {
    __shared__ __align__(16) u16 As[2 * 128 * 32];
    __shared__ __align__(16) u16 Bs[2 * 128 * 32];
    const int tid = threadIdx.x;
    const int wv = tid >> 6, ln = tid & 63;
    const int l16 = ln & 15, quad = ln >> 4;
    const int wm = (wv >> 1) << 6, wn = (wv & 1) << 6;
    const int m0 = blockIdx.y << 7, n0 = blockIdx.x << 7;
    const int srow = ln >> 2;
    const int scol = (((ln & 3) ^ ((ln >> 3) & 3)) << 3);  // swizzled source granule
    const u16 *Ag1 = p.A + (long long)(m0 + (wv << 4) + srow) * p.lda + scol;
    const u16 *Ag2 = Ag1 + (long long)64 * p.lda;
    const u16 *Bg1 = p.B + (long long)(n0 + (wv << 4) + srow) * p.ldb + scol;
    const u16 *Bg2 = Bg1 + (long long)64 * p.ldb;
    u16 *Al1 = &As[(wv << 4) << 5];
    u16 *Al2 = &As[((wv << 4) + 64) << 5];
    u16 *Bl1 = &Bs[(wv << 4) << 5];
    u16 *Bl2 = &Bs[((wv << 4) + 64) << 5];
    floatx4 zero = {0.f, 0.f, 0.f, 0.f};
    floatx4 acc[4][4];
#pragma unroll
    for (int i = 0; i < 4; i++)
#pragma unroll
        for (int j = 0; j < 4; j++) acc[i][j] = zero;

    const int rswz = ((quad ^ ((l16 >> 1) & 3)) << 3);  // read-side swizzle
    const int NT = p.K >> 5;  // BK=32; K>=512 at all call sites -> NT>=16

    auto stage = [&](int buf, int t) {  // 4 glds16 per wave
        const int k0 = t << 5;
        const int o = buf << 12;  // 4096 u16 per buffer
        glds16(Ag1 + k0, Al1 + o);
        glds16(Ag2 + k0, Al2 + o);
        glds16(Bg1 + k0, Bl1 + o);
        glds16(Bg2 + k0, Bl2 + o);
    };

    stage(0, 0);
    stage(1, 1);
    asm volatile("s_waitcnt vmcnt(4)" ::: "memory");  // buf0's 4 loads done
    __builtin_amdgcn_s_barrier();

    for (int t = 0; t < NT; t++) {
        const int o = (t & 1) << 12;
        bf16x8 av[4], bv[4];
#pragma unroll
        for (int mt = 0; mt < 4; mt++)
            av[mt] = __builtin_bit_cast(bf16x8,
                *(const uint4 *)&As[o + ((wm + (mt << 4) + l16) << 5) + rswz]);
#pragma unroll
        for (int nt = 0; nt < 4; nt++)
            bv[nt] = __builtin_bit_cast(bf16x8,
                *(const uint4 *)&Bs[o + ((wn + (nt << 4) + l16) << 5) + rswz]);
#pragma unroll
        for (int mt = 0; mt < 4; mt++)
#pragma unroll
            for (int nt = 0; nt < 4; nt++)
                acc[mt][nt] = __builtin_amdgcn_mfma_f32_16x16x32_bf16(av[mt], bv[nt],
                                                                      acc[mt][nt], 0, 0, 0);
        if (t + 1 < NT) {
            __builtin_amdgcn_sched_barrier(0);   // reads of buf complete before barrier
            __builtin_amdgcn_s_barrier();        // all waves done reading buf
            if (t + 2 < NT) {
                stage(t & 1, t + 2);             // re-stage retired buffer
                asm volatile("s_waitcnt vmcnt(4)" ::: "memory");  // next buf loads done
            } else {
                asm volatile("s_waitcnt vmcnt(0)" ::: "memory");  // tail drain
            }
            __builtin_amdgcn_s_barrier();        // next buf visible everywhere
            __builtin_amdgcn_sched_barrier(0);   // no hoisting of next reads above this
        }
    }

#pragma unroll
    for (int mt = 0; mt < 4; mt++)
#pragma unroll
        for (int nt = 0; nt < 4; nt++)
#pragma unroll
            for (int r = 0; r < 4; r++) {
                int gr = m0 + wm + (mt << 4) + (quad << 2) + r;
                int gc = n0 + wn + (nt << 4) + l16;
                float y = acc[mt][nt][r];
                if (p.bias) y += b2f(p.bias[gc]);
                if (gc < p.qcols) y *= p.qscale;
                if (p.mode == 0) {
                    p.C[(long long)gr * p.ldc + gc] = f2b(y);
                } else if (p.mode == 1) {
                    float s = 1.f / (1.f + __expf(1.f - y));
                    p.C[(long long)gr * p.ldc + gc] = f2b(y * s);
                } else {  // mode 2
                    long long idx = (long long)gr * p.ldc + gc;
                    float rv = p.resin_f32 ? ((const float *)p.resin)[idx]
                                           : b2f(((const u16 *)p.resin)[idx]);
                    float o = rv + y;
                    p.xr[idx] = o;
                    if (p.xb) p.xb[idx] = f2b(o);
                }
            }
}

// ---------------- flash attention v2 ----------------------------------------------
// grid (16 i-tiles, 32 z); 4 waves; wave wv owns q-rows i0+16wv..+15.
// Q fragments in registers (global load, no LDS). No-max softmax (|S|<=~2 by
// construction: weights std 0.02 -> exp safe). rel-shift bd remap via __shfl:
// compacted pos p = 15-r16+c; src lane (quad<<4)|((l16+15-r16)&15); reg nt+carry.
// LDS 41 KB -> 3 blocks/CU. 2 barriers per jt.
struct FK {
    const u16 *QU, *QV, *KH, *PPH, *VT;
    u16 *attno;
};

__global__ __launch_bounds__(256) void flash_k(FK p) {
    __shared__ __align__(16) u16 lds[20992];  // 41 KB
    u16 *Kh = lds;            // [0, 4096)      64 x 64 (swizzled granules)
    u16 *Ph = lds + 4096;     // [4096, 12288)  128 x 64 (swizzled)
    u16 *Vt = lds + 12288;    // [12288, 16384) 64 x 64 (swizzled)
    u16 *Pb = lds + 16384;    // [16384, 20992) 64 x 72 (padded, per-lane stores)

    const int tid = threadIdx.x;
    const int wv = tid >> 6, ln = tid & 63;
    const int l16 = ln & 15, quad = ln >> 4;
    const int zg = blockIdx.y;
    const int i0 = blockIdx.x << 6;
    const u16 *kh0 = p.KH + (long long)zg * 65536;
    const u16 *ph0 = p.PPH + (long long)(zg & 7) * 131072;
    const u16 *vt0 = p.VT + (long long)zg * 65536;

    // Q fragments from global into registers (A-layout: row l16, k quad*8+kk*32)
    const long long qoff = (long long)zg * 65536 + (long long)(i0 + (wv << 4) + l16) * 64 + (quad << 3);
    bf16x8 aqu[2], aqv[2];
#pragma unroll
    for (int kk = 0; kk < 2; kk++) {
        aqu[kk] = __builtin_bit_cast(bf16x8, *(const uint4 *)(p.QU + qoff + (kk << 5)));
        aqv[kk] = __builtin_bit_cast(bf16x8, *(const uint4 *)(p.QV + qoff + (kk << 5)));
    }

    float lacc[4];
    floatx4 accO[4];
    floatx4 zero = {0.f, 0.f, 0.f, 0.f};
#pragma unroll
    for (int e = 0; e < 4; e++) lacc[e] = 0.f;
#pragma unroll
    for (int i = 0; i < 4; i++) accO[i] = zero;

    const int r16q = quad << 2;  // r16 base for this lane's quad

    for (int jt = 0; jt < 16; jt++) {
        const int j0 = jt << 6;
        const int m_start = 960 - i0 + j0;  // [0,1920]; +127 <= 2047 (pph pad row)
        __syncthreads();  // prior iter's LDS reads complete
#pragma unroll
        for (int ps = 0; ps < 2; ps++) {
            int g = ps * 256 + tid;
            int row = g >> 3;
            int src = ((g & 7) ^ (row & 7)) << 3;
            glds16(kh0 + ((j0 + row) << 6) + src, Kh + g * 8);
            glds16(vt0 + (row << 10) + j0 + src, Vt + g * 8);
        }
#pragma unroll
        for (int ps = 0; ps < 4; ps++) {
            int g = ps * 256 + tid;
            int row = g >> 3;
            int src = ((g & 7) ^ (row & 7)) << 3;
            glds16(ph0 + ((m_start + row) << 6) + src, Ph + g * 8);
        }
        __syncthreads();  // staged tiles visible

        // ---- score MFMAs
        floatx4 aS[4], aB[5];
#pragma unroll
        for (int i = 0; i < 4; i++) aS[i] = zero;
#pragma unroll
        for (int i = 0; i < 5; i++) aB[i] = zero;
#pragma unroll
        for (int kk = 0; kk < 2; kk++) {
            const int swz = ((((kk << 2) | quad) ^ (l16 & 7)) << 3);
#pragma unroll
            for (int nt = 0; nt < 4; nt++) {
                bf16x8 bf = __builtin_bit_cast(bf16x8,
                    *(const uint4 *)&Kh[(((nt << 4) | l16) << 6) + swz]);
                aS[nt] = __builtin_amdgcn_mfma_f32_16x16x32_bf16(aqu[kk], bf, aS[nt], 0, 0, 0);
            }
#pragma unroll
            for (int rt = 0; rt < 5; rt++) {
                bf16x8 bf = __builtin_bit_cast(bf16x8,
                    *(const uint4 *)&Ph[((((rt + 3 - wv) << 4) | l16) << 6) + swz]);
                aB[rt] = __builtin_amdgcn_mfma_f32_16x16x32_bf16(aqv[kk], bf, aB[rt], 0, 0, 0);
            }
        }

        // ---- assemble S = aS + shfl-remapped bd; no-max softmax; Pb write
#pragma unroll
        for (int e = 0; e < 4; e++) {
            const int r16 = r16q + e;
            const int t = l16 + 15 - r16;          // [0,30]
            const int srcl = (quad << 4) | (t & 15);
            const int carry = t >> 4;
            float ps = 0.f;
#pragma unroll
            for (int nt = 0; nt < 4; nt++) {
                float vlo = __shfl(aB[nt][e], srcl, 64);
                float vhi = __shfl(aB[nt + 1][e], srcl, 64);
                float bd = carry ? vhi : vlo;
                float pe = __expf(aS[nt][e] + bd);
                ps += pe;
                Pb[(((wv << 4) + r16) * 72) + (nt << 4) + l16] = f2b(pe);
            }
            lacc[e] += ps;
        }
        // Pb rows are wave-private: in-wave RAW handled by lgkmcnt, no barrier.

        // ---- PV MFMAs: accO += P(16x64) x V(64x64)
#pragma unroll
        for (int kk = 0; kk < 2; kk++) {
            const int swz = ((((kk << 2) | quad) ^ (l16 & 7)) << 3);
            bf16x8 ap = __builtin_bit_cast(bf16x8,
                *(const uint4 *)&Pb[(((wv << 4) | l16) * 72) + (kk << 5) + (quad << 3)]);
#pragma unroll
            for (int nd = 0; nd < 4; nd++) {
                bf16x8 bv = __builtin_bit_cast(bf16x8,
                    *(const uint4 *)&Vt[(((nd << 4) | l16) << 6) + swz]);
                accO[nd] = __builtin_amdgcn_mfma_f32_16x16x32_bf16(ap, bv, accO[nd], 0, 0, 0);
            }
        }
    }

    // ---- epilogue: reduce l across quad (cols), then O/l -> attno (t, b, h*64+d)
    const int b = zg >> 3, h = zg & 7;
#pragma unroll
    for (int e = 0; e < 4; e++) {
#pragma unroll
        for (int msk = 1; msk < 16; msk <<= 1) lacc[e] += __shfl_xor(lacc[e], msk, 64);
        float inv = 1.f / lacc[e];
        int t = i0 + (wv << 4) + (quad << 2) + e;
#pragma unroll
        for (int nd = 0; nd < 4; nd++) {
            int d = (nd << 4) + l16;
            p.attno[(long long)(t * B_ + b) * E_ + h * 64 + d] = f2b(accO[nd][e] * inv);
        }
    }
}

// ---------------- small helper kernels -------------------------------------------

__global__ __launch_bounds__(256) void repack_pos_k(const u16 *pp, u16 *pph) {
    int gid = blockIdx.x * 256 + threadIdx.x;  // 8*2048*64 = 1M
    int h = gid >> 17, rem = gid & 131071;
    int m = rem >> 6, d = rem & 63;
    pph[gid] = (m < 2 * T_ - 1) ? pp[(long long)m * E_ + h * 64 + d] : (u16)0;
}

__global__ __launch_bounds__(256) void repack_qkv_k(const u16 *qkv, const u16 *u, const u16 *v,
                                                    u16 *QU, u16 *QV, u16 *KH) {
    int gid = blockIdx.x * 256 + threadIdx.x;  // 32*1024*64 = 2M
    int z = gid >> 16, rem = gid & 65535;
    int t = rem >> 6, d = rem & 63;
    int b = z >> 3, h = z & 7;
    long long base = (long long)(t * B_ + b) * (3 * E_) + h * 64 + d;
    float q = b2f(qkv[base]);
    QU[gid] = f2b(q + b2f(u[h * 64 + d]));
    QV[gid] = f2b(q + b2f(v[h * 64 + d]));
    KH[gid] = qkv[base + E_];
}

__global__ __launch_bounds__(256) void transpose_v_k(const u16 *qkv, u16 *VT) {
    __shared__ u16 lds[64 * 65];
    int z = blockIdx.y, t0 = blockIdx.x * 64;
    int b = z >> 3, h = z & 7;
    int tid = threadIdx.x, wv = tid >> 6, ln = tid & 63;
    for (int rr = 0; rr < 16; rr++) {
        int tl = wv * 16 + rr;
        lds[ln * 65 + tl] = qkv[(long long)((t0 + tl) * B_ + b) * (3 * E_) + 2 * E_ + h * 64 + ln];
    }
    __syncthreads();
    int d = tid >> 2, seg = tid & 3;
    long long ob = (long long)(z * 64 + d) * T_ + t0 + seg * 16;
    for (int ii = 0; ii < 16; ii++) VT[ob + ii] = lds[d * 65 + seg * 16 + ii];
}

__global__ __launch_bounds__(256) void glu_k(const u16 *y1, u16 *ch) {
    int gid = blockIdx.x * 256 + threadIdx.x;  // 4096*512
    int r = gid >> 9, c = gid & 511;
    float a = b2f(y1[(long long)r * (2 * E_) + c]);
    float g = b2f(y1[(long long)r * (2 * E_) + E_ + c]);
    ch[gid] = f2b(a * (1.f / (1.f + __expf(-g))));
}

// depthwise conv — register sliding window. Thread = (b, channel-pair) x 8 t's.
__global__ __launch_bounds__(256) void dwconv_k(const u16 *ch, const u16 *w, const u16 *bias,
                                                u16 *cd) {
    const int cp = threadIdx.x;
    const int b = blockIdx.x >> 7;
    const int t0 = (blockIdx.x & 127) << 3;
    const int c0 = cp << 1;
    float in0[38], in1[38];
#pragma unroll
    for (int j = 0; j < 38; j++) {
        int tt = t0 - 15 + j;
        u32 v = 0;
        if (tt >= 0 && tt < T_) v = *(const u32 *)&ch[tt * 2048 + b * 512 + c0];
        in0[j] = b2f((u16)(v & 0xffff));
        in1[j] = b2f((u16)(v >> 16));
    }
    float w0[KW_], w1[KW_];
#pragma unroll
    for (int kk = 0; kk < KW_; kk++) {
        w0[kk] = b2f(w[c0 * KW_ + kk]);
        w1[kk] = b2f(w[c0 * KW_ + KW_ + kk]);
    }
    float bi0 = b2f(bias[c0]), bi1 = b2f(bias[c0 + 1]);
#pragma unroll
    for (int t = 0; t < 8; t++) {
        float a0 = bi0, a1 = bi1;
#pragma unroll
        for (int kk = 0; kk < KW_; kk++) {
            a0 += in0[t + kk] * w0[kk];
            a1 += in1[t + kk] * w1[kk];
        }
        float s0 = 1.f / (1.f + __expf(1.f - a0));
        float s1 = 1.f / (1.f + __expf(1.f - a1));
        u32 o = (u32)f2b(a0 * s0) | ((u32)f2b(a1 * s1) << 16);
        *(u32 *)&cd[(t0 + t) * 2048 + b * 512 + c0] = o;
    }
}

// BasicNorm -> FLOAT32 output. One wave per row.
__global__ __launch_bounds__(256) void norm_k(const float *xr, const float *epsp, float *out) {
    int wv = threadIdx.x >> 6, ln = threadIdx.x & 63;
    long long row = blockIdx.x * 4 + wv;
    const float *x = xr + row * E_;
    float vals[8], ss = 0.f;
#pragma unroll
    for (int i = 0; i < 8; i++) {
        vals[i] = x[ln + (i << 6)];
        ss += vals[i] * vals[i];
    }
#pragma unroll
    for (int m = 32; m; m >>= 1) ss += __shfl_xor(ss, m, 64);
    float sc = rsqrtf(ss * (1.f / (float)E_) + __expf(epsp[0]));
    float *o = out + row * E_;
#pragma unroll
    for (int i = 0; i < 8; i++) o[ln + (i << 6)] = vals[i] * sc;
}

// ---------------- host ------------------------------------------------------------

extern "C" void kernel_launch(void *const *d_in, const int *in_sizes, int n_in,
                              void *d_out, int out_size, void *d_ws, size_t ws_size,
                              hipStream_t stream) {
    const size_t MB = (size_t)1 << 20;
    static const long long EXPECT[24] = {
        2097152, 1048064, 786432, 1536, 262144, 512, 262144, 512, 512,
        1048576, 2048, 1048576, 512, 1048576, 2048, 1048576, 512,
        524288, 1024, 15872, 512, 262144, 512, 1};
    const size_t NEED = 93 * MB;

    float code = 0.f;
    if (n_in != 24) {
        code = 1000.f + (float)n_in;
    } else {
        for (int i = 0; i < 24; i++) {
            if ((long long)in_sizes[i] != EXPECT[i]) { code = 2000.f + 64.f * i; break; }
        }
    }
    if (code == 0.f && out_size != 2097152) code = 3000.f;
    if (code == 0.f && ws_size < NEED) code = 5000.f + (float)(ws_size / MB);
    if (code != 0.f) {
        long long n = (long long)out_size;
        fill_k<<<dim3((unsigned)((n + 255) / 256)), dim3(256), 0, stream>>>((float *)d_out, n, code);
        return;
    }

    char *w = (char *)d_ws;
    int *flag = (int *)(w + 0);
    u16 *cv = (u16 *)(w + 1 * MB);
    float *xr = (float *)(w + 21 * MB);
    u16 *xb = (u16 *)(w + 29 * MB);
    u16 *h1 = (u16 *)(w + 33 * MB);
    u16 *qkv = (u16 *)(w + 49 * MB);
    u16 *y1 = (u16 *)(w + 49 * MB);
    u16 *pp = (u16 *)(w + 61 * MB);
    u16 *pph = (u16 *)(w + 63 * MB);
    u16 *QU = (u16 *)(w + 65 * MB);
    u16 *QV = (u16 *)(w + 69 * MB);
    u16 *KH = (u16 *)(w + 73 * MB);
    u16 *VT = (u16 *)(w + 77 * MB);
    u16 *attno = (u16 *)(w + 81 * MB);
    u16 *ch = (u16 *)(w + 85 * MB);
    u16 *cd = (u16 *)(w + 89 * MB);

    detect_k<<<dim3(1), dim3(256), 0, stream>>>((const u16 *)d_in[0], flag);
    CVT c;
    c.pre[0] = 0;
    for (int i = 0; i < 24; i++) {
        c.in[i] = d_in[i];
        c.pre[i + 1] = c.pre[i] + in_sizes[i];
    }
    long long total = c.pre[24];
    convert_k<<<dim3((unsigned)((total + 255) / 256)), dim3(256), 0, stream>>>(c, cv, flag, total);

    const u16 *src = cv + c.pre[0];
    const u16 *pos_emb = cv + c.pre[1];
    const u16 *w_qkv = cv + c.pre[2];
    const u16 *b_qkv = cv + c.pre[3];
    const u16 *w_o = cv + c.pre[4];
    const u16 *b_o = cv + c.pre[5];
    const u16 *w_pos = cv + c.pre[6];
    const u16 *u_bias = cv + c.pre[7];
    const u16 *v_bias = cv + c.pre[8];
    const u16 *ffm_w1 = cv + c.pre[9];
    const u16 *ffm_b1 = cv + c.pre[10];
    const u16 *ffm_w2 = cv + c.pre[11];
    const u16 *ffm_b2 = cv + c.pre[12];
    const u16 *ff_w1 = cv + c.pre[13];
    const u16 *ff_b1 = cv + c.pre[14];
    const u16 *ff_w2 = cv + c.pre[15];
    const u16 *ff_b2 = cv + c.pre[16];
    const u16 *pw1_w = cv + c.pre[17];
    const u16 *pw1_b = cv + c.pre[18];
    const u16 *dw_w = cv + c.pre[19];
    const u16 *dw_b = cv + c.pre[20];
    const u16 *pw2_w = cv + c.pre[21];
    const u16 *pw2_b = cv + c.pre[22];

    auto mk = [](const void *A, int lda, const void *B, int ldb, void *C, int ldc,
                 const void *bias, int M, int N, int K, int mode) {
        GP p;
        memset(&p, 0, sizeof(p));
        p.A = (const u16 *)A; p.B = (const u16 *)B; p.C = (u16 *)C; p.bias = (const u16 *)bias;
        p.M = M; p.N = N; p.K = K; p.lda = lda; p.ldb = ldb; p.ldc = ldc; p.mode = mode;
        p.qscale = 1.f;
        return p;
    };
    auto launch = [&](GP p) {
        dim3 g((p.N + 63) / 64, (p.M + 63) / 64, 1);
        gemm_nt<<<g, dim3(256), 0, stream>>>(p);
    };
    auto launch128 = [&](GP p) {
        dim3 g(p.N >> 7, p.M >> 7, 1);
        gemm_nt128<<<g, dim3(256), 0, stream>>>(p);
    };

    const int M = T_ * B_;  // 4096

    // ---- macaron FFN: x1 = src + W2 @ dswish(W1 @ src + b1) + b2
    { GP p = mk(src, E_, ffm_w1, E_, h1, DFF_, ffm_b1, M, DFF_, E_, 1); launch128(p); }
    { GP p = mk(h1, DFF_, ffm_w2, DFF_, nullptr, E_, ffm_b2, M, E_, DFF_, 2);
      p.resin = d_in[0]; p.resin_f32 = 1; p.xr = xr; p.xb = xb; launch(p); }

    // ---- attention projections
    { GP p = mk(xb, E_, w_qkv, E_, qkv, 3 * E_, b_qkv, M, 3 * E_, E_, 0);
      p.qcols = E_; p.qscale = 0.125f; launch128(p); }
    { GP p = mk(pos_emb, E_, w_pos, E_, pp, E_, nullptr, 2 * T_ - 1, E_, E_, 0); launch(p); }
    repack_pos_k<<<dim3(4096), dim3(256), 0, stream>>>(pp, pph);
    repack_qkv_k<<<dim3(8192), dim3(256), 0, stream>>>(qkv, u_bias, v_bias, QU, QV, KH);
    transpose_v_k<<<dim3(16, 32), dim3(256), 0, stream>>>(qkv, VT);

    // ---- flash attention (no S materialization)
    {
        FK f;
        f.QU = QU; f.QV = QV; f.KH = KH; f.PPH = pph; f.VT = VT; f.attno = attno;
        flash_k<<<dim3(16, 32), dim3(256), 0, stream>>>(f);
    }

    // ---- out projection + residual -> x2
    { GP p = mk(attno, E_, w_o, E_, nullptr, E_, b_o, M, E_, E_, 2);
      p.resin = xr; p.resin_f32 = 1; p.xr = xr; p.xb = xb; launch(p); }

    // ---- conv module
    { GP p = mk(xb, E_, pw1_w, E_, y1, 2 * E_, pw1_b, M, 2 * E_, E_, 0); launch128(p); }
    glu_k<<<dim3(8192), dim3(256), 0, stream>>>(y1, ch);
    dwconv_k<<<dim3(512), dim3(256), 0, stream>>>(ch, dw_w, dw_b, cd);
    { GP p = mk(cd, E_, pw2_w, E_, nullptr, E_, pw2_b, M, E_, E_, 2);
      p.resin = xr; p.resin_f32 = 1; p.xr = xr; p.xb = xb; launch(p); }

    // ---- second FFN
    { GP p = mk(xb, E_, ff_w1, E_, h1, DFF_, ff_b1, M, DFF_, E_, 1); launch128(p); }
    { GP p = mk(h1, DFF_, ff_w2, DFF_, nullptr, E_, ff_b2, M, E_, DFF_, 2);
      p.resin = xr; p.resin_f32 = 1; p.xr = xr; p.xb = nullptr; launch(p); }

    // ---- final BasicNorm -> d_out (FLOAT32)
    norm_k<<<dim3(M / 4), dim3(256), 0, stream>>>(xr, (const float *)d_in[23], (float *)d_out);
}

// Round 2
// 447.658 us; speedup vs baseline: 1.0087x; 1.0087x over previous
//
#include <hip/hip_runtime.h>
#include <string.h>

// Conformer encoder layer, MI355X gfx950 — ROUND 12.
// R11: 452 us. gemm_nt128 dropped below flash_k (pipeline worked); flash_k
// now top at 45 us/dispatch: MfmaUtil 11%, VALU 28%, HBM 14%, occ 18% ->
// exposed staging latency (syncthreads vmcnt(0) per jt) + cross-XCD K/V
// refetch (FETCH 45MB vs 18MB footprint).
// Changes: flash_k double-buffered K/V/P staging (73KB LDS, 2 blocks/CU),
// stage(jt+1) before compute(jt), vmcnt(0) only after compute (full-phase
// slack), setprio around MFMA clusters, XCD-cluster block swizzle (each XCD
// owns 4 zg -> K/V/pph fit 4MB L2). GEMMs -> 3-buffer pipeline (2 compute
// phases of load slack, vmcnt(8/4/0)). repack_pos fused into pos GEMM
// (mode 3). T=1024 B=4 E=512 H=8 D=64 DFF=2048 K=31. Workspace: 93 MB.

#define T_ 1024
#define B_ 4
#define E_ 512
#define H_ 8
#define DFF_ 2048
#define KW_ 31

typedef unsigned short u16;
typedef unsigned int u32;
typedef __bf16 bf16x8 __attribute__((ext_vector_type(8)));
typedef float floatx4 __attribute__((ext_vector_type(4)));

__device__ __forceinline__ float b2f(u16 u) {
    return __uint_as_float(((u32)u) << 16);
}
__device__ __forceinline__ u16 f2b(float f) {
    u32 i = __float_as_uint(f);
    u32 r = (i + 0x7fffu + ((i >> 16) & 1u)) >> 16;  // RNE, finite inputs only
    return (u16)r;
}

__device__ __forceinline__ void glds16(const u16 *g, u16 *l) {
    __builtin_amdgcn_global_load_lds((const __attribute__((address_space(1))) void *)g,
                                     (__attribute__((address_space(3))) void *)l, 16, 0, 0);
}

// ---------------- diagnostic fill (f32 out) ---------------------------------------
__global__ __launch_bounds__(256) void fill_k(float *out, long long n, float val) {
    long long g = (long long)blockIdx.x * 256 + threadIdx.x;
    if (g < n) out[g] = val;
}

// ---------------- input dtype detect + convert ------------------------------------
__global__ __launch_bounds__(256) void detect_k(const u16 *src16, int *flag) {
    __shared__ int sh[256];
    int tid = threadIdx.x;
    int cnt = 0;
    for (int i = tid; i < 4096; i += 256) {
        u16 x = src16[2 * i];
        int e = (x >> 7) & 0xFF;
        cnt += (e == 0 || (e >= 0x70 && e <= 0x8F)) ? 1 : 0;
    }
    sh[tid] = cnt;
    __syncthreads();
    for (int s = 128; s; s >>= 1) {
        if (tid < s) sh[tid] += sh[tid + s];
        __syncthreads();
    }
    if (tid == 0) *flag = (sh[0] < 2048) ? 1 : 0;  // 1 = f32 inputs, 0 = bf16
}

struct CVT {
    const void *in[24];
    long long pre[25];
};

__global__ __launch_bounds__(256) void convert_k(CVT c, u16 *dst, const int *flag,
                                                 long long total) {
    long long g = (long long)blockIdx.x * 256 + threadIdx.x;
    if (g >= total) return;
    int s = 0;
#pragma unroll
    for (int i = 1; i < 25; i++) s += (g >= c.pre[i]) ? 1 : 0;
    long long l = g - c.pre[s];
    int f = *flag;
    u16 v = f ? f2b(((const float *)c.in[s])[l]) : ((const u16 *)c.in[s])[l];
    dst[g] = v;
}

// ---------------- generic NT GEMM: C(M,N) = A(M,K) @ B(N,K)^T ----------------------
struct GP {
    const u16 *A, *B;
    u16 *C;
    const u16 *bias;
    const void *resin;     // mode 2: residual input (bf16 or f32)
    float *xr;             // mode 2: f32 residual out
    u16 *xb;               // mode 2: bf16 copy out (may be null)
    int M, N, K, lda, ldb, ldc, mode, qcols, resin_f32;
    float qscale;
};

// 64x64 tile, BK=64, glds16 staging w/ XOR swizzle (conflict-free b128 reads).
// R12: 3-buffer pipeline (2 compute phases of slack), counted vmcnt(8/4/0).
// modes: 0 = bf16 store; 1 = DoubleSwish; 2 = residual; 3 = pph repack store
__global__ __launch_bounds__(256) void gemm_nt(GP p) {
    __shared__ __align__(16) u16 As[3 * 64 * 64];
    __shared__ __align__(16) u16 Bs[3 * 64 * 64];
    const int tid = threadIdx.x;
    const int wv = tid >> 6, ln = tid & 63;
    const int l16 = ln & 15, quad = ln >> 4;
    const int m0 = blockIdx.y * 64, n0 = blockIdx.x * 64;
    floatx4 zero = {0.f, 0.f, 0.f, 0.f};
    floatx4 acc[4];
#pragma unroll
    for (int i = 0; i < 4; i++) acc[i] = zero;

    const int NT = p.K >> 6;  // BK=64; all call-site K are multiples of 64, K>=512

    // stage = 4 glds16 per wave (A x2, B x2). Row-clamped A: no divergence,
    // uniform per-wave vmcnt count. Clamped rows masked at store.
    auto stage = [&](int bidx, int t) {
        const int k0 = t << 6;
        const int o = bidx << 12;  // 4096 u16 per buffer
#pragma unroll
        for (int ps = 0; ps < 2; ps++) {
            int g = ps * 256 + tid;
            int row = g >> 3;
            int src = ((g & 7) ^ (row & 7)) << 3;
            int ra = m0 + row;
            if (ra > p.M - 1) ra = p.M - 1;
            glds16(p.A + (long long)ra * p.lda + k0 + src, As + o + g * 8);
            glds16(p.B + (long long)(n0 + row) * p.ldb + k0 + src, Bs + o + g * 8);
        }
    };

    stage(0, 0);
    stage(1, 1);
    stage(2, 2);
    asm volatile("s_waitcnt vmcnt(8)" ::: "memory");  // buf0's 4 loads done
    __builtin_amdgcn_s_barrier();

    int cb = 0;  // t % 3
    for (int t = 0; t < NT; t++) {
        const int o = cb << 12;
#pragma unroll
        for (int kk = 0; kk < 2; kk++) {
            const int swz = ((((kk << 2) | quad) ^ (l16 & 7)) << 3);
            bf16x8 af = __builtin_bit_cast(bf16x8,
                *(const uint4 *)&As[o + (((wv << 4) | l16) << 6) + swz]);
#pragma unroll
            for (int nt = 0; nt < 4; nt++) {
                bf16x8 bf = __builtin_bit_cast(bf16x8,
                    *(const uint4 *)&Bs[o + (((nt << 4) | l16) << 6) + swz]);
                acc[nt] = __builtin_amdgcn_mfma_f32_16x16x32_bf16(af, bf, acc[nt], 0, 0, 0);
            }
        }
        if (t + 1 < NT) {
            __builtin_amdgcn_sched_barrier(0);   // reads of buf complete before barrier
            __builtin_amdgcn_s_barrier();        // all waves done reading buf t
            if (t + 3 < NT) {
                stage(cb, t + 3);                // re-stage retired buffer
                asm volatile("s_waitcnt vmcnt(8)" ::: "memory");  // buf t+1 done
            } else if (t + 2 < NT) {
                asm volatile("s_waitcnt vmcnt(4)" ::: "memory");
            } else {
                asm volatile("s_waitcnt vmcnt(0)" ::: "memory");
            }
            __builtin_amdgcn_s_barrier();        // buf t+1 visible everywhere
            __builtin_amdgcn_sched_barrier(0);   // no hoisting of next reads above this
        }
        cb = (cb == 2) ? 0 : cb + 1;
    }

#pragma unroll
    for (int nt = 0; nt < 4; nt++) {
#pragma unroll
        for (int r = 0; r < 4; r++) {
            int gr = m0 + (wv << 4) + (quad << 2) + r;
            int gc = n0 + (nt << 4) + l16;
            bool oob = gr >= p.M;
            if (oob && p.mode != 3) continue;
            float y = 0.f;
            if (!oob) {
                y = acc[nt][r];
                if (p.bias) y += b2f(p.bias[gc]);
                if (gc < p.qcols) y *= p.qscale;
            }
            if (p.mode == 3) {
                // fused repack_pos: C = pph, layout [(h*2048 + m)*64 + d]
                p.C[((gc >> 6) << 17) + (gr << 6) + (gc & 63)] = f2b(y);
            } else if (p.mode == 0) {
                p.C[(long long)gr * p.ldc + gc] = f2b(y);
            } else if (p.mode == 1) {
                float s = 1.f / (1.f + __expf(1.f - y));  // x*sigmoid(x-1)
                p.C[(long long)gr * p.ldc + gc] = f2b(y * s);
            } else {  // mode 2
                long long idx = (long long)gr * p.ldc + gc;
                float rv = p.resin_f32 ? ((const float *)p.resin)[idx]
                                       : b2f(((const u16 *)p.resin)[idx]);
                float o = rv + y;
                p.xr[idx] = o;
                if (p.xb) p.xb[idx] = f2b(o);
            }
        }
    }
}

// ---------------- 128x128 m97-style GEMM (z=1, M%128==0, N%128==0, K%32==0) --------
// v2: XOR swizzle on 4-granule rows kills the 8-way read conflicts.
// R12: 3-buffer pipeline, counted vmcnt(8/4/0).
__global__ __launch_bounds__(256) void gemm_nt128(GP p) {
    __shared__ __align__(16) u16 As[3 * 128 * 32];
    __shared__ __align__(16) u16 Bs[3 * 128 * 32];
    const int tid = threadIdx.x;
    const int wv = tid >> 6, ln = tid & 63;
    const int l16 = ln & 15, quad = ln >> 4;
    const int wm = (wv >> 1) << 6, wn = (wv & 1) << 6;
    const int m0 = blockIdx.y << 7, n0 = blockIdx.x << 7;
    const int srow = ln >> 2;
    const int scol = (((ln & 3) ^ ((ln >> 3) & 3)) << 3);  // swizzled source granule
    const u16 *Ag1 = p.A + (long long)(m0 + (wv << 4) + srow) * p.lda + scol;
    const u16 *Ag2 = Ag1 + (long long)64 * p.lda;
    const u16 *Bg1 = p.B + (long long)(n0 + (wv << 4) + srow) * p.ldb + scol;
    const u16 *Bg2 = Bg1 + (long long)64 * p.ldb;
    u16 *Al1 = &As[(wv << 4) << 5];
    u16 *Al2 = &As[((wv << 4) + 64) << 5];
    u16 *Bl1 = &Bs[(wv << 4) << 5];
    u16 *Bl2 = &Bs[((wv << 4) + 64) << 5];
    floatx4 zero = {0.f, 0.f, 0.f, 0.f};
    floatx4 acc[4][4];
#pragma unroll
    for (int i = 0; i < 4; i++)
#pragma unroll
        for (int j = 0; j < 4; j++) acc[i][j] = zero;

    const int rswz = ((quad ^ ((l16 >> 1) & 3)) << 3);  // read-side swizzle
    const int NT = p.K >> 5;  // BK=32; K>=512 at all call sites -> NT>=16

    auto stage = [&](int bidx, int t) {  // 4 glds16 per wave
        const int k0 = t << 5;
        const int o = bidx << 12;  // 4096 u16 per buffer
        glds16(Ag1 + k0, Al1 + o);
        glds16(Ag2 + k0, Al2 + o);
        glds16(Bg1 + k0, Bl1 + o);
        glds16(Bg2 + k0, Bl2 + o);
    };

    stage(0, 0);
    stage(1, 1);
    stage(2, 2);
    asm volatile("s_waitcnt vmcnt(8)" ::: "memory");  // buf0's 4 loads done
    __builtin_amdgcn_s_barrier();

    int cb = 0;  // t % 3
    for (int t = 0; t < NT; t++) {
        const int o = cb << 12;
        bf16x8 av[4], bv[4];
#pragma unroll
        for (int mt = 0; mt < 4; mt++)
            av[mt] = __builtin_bit_cast(bf16x8,
                *(const uint4 *)&As[o + ((wm + (mt << 4) + l16) << 5) + rswz]);
#pragma unroll
        for (int nt = 0; nt < 4; nt++)
            bv[nt] = __builtin_bit_cast(bf16x8,
                *(const uint4 *)&Bs[o + ((wn + (nt << 4) + l16) << 5) + rswz]);
#pragma unroll
        for (int mt = 0; mt < 4; mt++)
#pragma unroll
            for (int nt = 0; nt < 4; nt++)
                acc[mt][nt] = __builtin_amdgcn_mfma_f32_16x16x32_bf16(av[mt], bv[nt],
                                                                      acc[mt][nt], 0, 0, 0);
        if (t + 1 < NT) {
            __builtin_amdgcn_sched_barrier(0);   // reads of buf complete before barrier
            __builtin_amdgcn_s_barrier();        // all waves done reading buf t
            if (t + 3 < NT) {
                stage(cb, t + 3);                // re-stage retired buffer
                asm volatile("s_waitcnt vmcnt(8)" ::: "memory");  // buf t+1 done
            } else if (t + 2 < NT) {
                asm volatile("s_waitcnt vmcnt(4)" ::: "memory");
            } else {
                asm volatile("s_waitcnt vmcnt(0)" ::: "memory");
            }
            __builtin_amdgcn_s_barrier();        // buf t+1 visible everywhere
            __builtin_amdgcn_sched_barrier(0);   // no hoisting of next reads above this
        }
        cb = (cb == 2) ? 0 : cb + 1;
    }

#pragma unroll
    for (int mt = 0; mt < 4; mt++)
#pragma unroll
        for (int nt = 0; nt < 4; nt++)
#pragma unroll
            for (int r = 0; r < 4; r++) {
                int gr = m0 + wm + (mt << 4) + (quad << 2) + r;
                int gc = n0 + wn + (nt << 4) + l16;
                float y = acc[mt][nt][r];
                if (p.bias) y += b2f(p.bias[gc]);
                if (gc < p.qcols) y *= p.qscale;
                if (p.mode == 0) {
                    p.C[(long long)gr * p.ldc + gc] = f2b(y);
                } else if (p.mode == 1) {
                    float s = 1.f / (1.f + __expf(1.f - y));
                    p.C[(long long)gr * p.ldc + gc] = f2b(y * s);
                } else {  // mode 2
                    long long idx = (long long)gr * p.ldc + gc;
                    float rv = p.resin_f32 ? ((const float *)p.resin)[idx]
                                           : b2f(((const u16 *)p.resin)[idx]);
                    float o = rv + y;
                    p.xr[idx] = o;
                    if (p.xb) p.xb[idx] = f2b(o);
                }
            }
}

// ---------------- flash attention v3 ----------------------------------------------
// grid 512 blocks (XCD-cluster swizzled: each XCD owns 4 zg -> K/V/pph L2-fit).
// 4 waves; wave wv owns q-rows i0+16wv..+15. Q in registers. No-max softmax
// (|S|<=~2 by construction). rel-shift bd remap via __shfl. R12: double-
// buffered K/V/P staging (73KB LDS, 2 blocks/CU), stage(jt+1) issued before
// compute(jt), vmcnt(0) after compute (full-phase slack), setprio on MFMAs.
struct FK {
    const u16 *QU, *QV, *KH, *PPH, *VT;
    u16 *attno;
};

__global__ __launch_bounds__(256) void flash_k(FK p) {
    // per-buffer (16384 u16): Kh [0,4096) 64x64 | Vt [4096,8192) 64x64 |
    // Ph [8192,16384) 128x64. Pb at 32768: 64x72 (padded, per-lane stores).
    __shared__ __align__(16) u16 lds[2 * 16384 + 4608];  // 73 KB

    const int tid = threadIdx.x;
    const int wv = tid >> 6, ln = tid & 63;
    const int l16 = ln & 15, quad = ln >> 4;
    const int lid = blockIdx.y * 16 + blockIdx.x;
    const int nid = (lid & 7) * 64 + (lid >> 3);  // XCD-cluster swizzle (bijective)
    const int zg = nid >> 4;
    const int i0 = (nid & 15) << 6;
    const u16 *kh0 = p.KH + (long long)zg * 65536;
    const u16 *ph0 = p.PPH + (long long)(zg & 7) * 131072;
    const u16 *vt0 = p.VT + (long long)zg * 65536;
    u16 *Pb = lds + 32768;

    auto stage = [&](int buf, int jt) {  // 8 glds16 per wave
        const int j0 = jt << 6;
        const int m_start = 960 - i0 + j0;  // [0,1920]; +127 <= 2047 (pph pad row)
        u16 *Kh = lds + (buf << 14);
        u16 *Vt = Kh + 4096;
        u16 *Ph = Kh + 8192;
#pragma unroll
        for (int ps = 0; ps < 2; ps++) {
            int g = ps * 256 + tid;
            int row = g >> 3;
            int src = ((g & 7) ^ (row & 7)) << 3;
            glds16(kh0 + ((j0 + row) << 6) + src, Kh + g * 8);
            glds16(vt0 + (row << 10) + j0 + src, Vt + g * 8);
        }
#pragma unroll
        for (int ps = 0; ps < 4; ps++) {
            int g = ps * 256 + tid;
            int row = g >> 3;
            int src = ((g & 7) ^ (row & 7)) << 3;
            glds16(ph0 + ((m_start + row) << 6) + src, Ph + g * 8);
        }
    };

    // Q fragments from global into registers (A-layout: row l16, k quad*8+kk*32)
    const long long qoff = (long long)zg * 65536 + (long long)(i0 + (wv << 4) + l16) * 64 + (quad << 3);
    bf16x8 aqu[2], aqv[2];
#pragma unroll
    for (int kk = 0; kk < 2; kk++) {
        aqu[kk] = __builtin_bit_cast(bf16x8, *(const uint4 *)(p.QU + qoff + (kk << 5)));
        aqv[kk] = __builtin_bit_cast(bf16x8, *(const uint4 *)(p.QV + qoff + (kk << 5)));
    }

    stage(0, 0);
    asm volatile("s_waitcnt vmcnt(0)" ::: "memory");  // buf0 staged (+ Q loads done)
    __builtin_amdgcn_s_barrier();

    float lacc[4];
    floatx4 accO[4];
    floatx4 zero = {0.f, 0.f, 0.f, 0.f};
#pragma unroll
    for (int e = 0; e < 4; e++) lacc[e] = 0.f;
#pragma unroll
    for (int i = 0; i < 4; i++) accO[i] = zero;

    const int r16q = quad << 2;  // r16 base for this lane's quad

    for (int jt = 0; jt < 16; jt++) {
        if (jt + 1 < 16) stage((jt + 1) & 1, jt + 1);  // prefetch under compute
        __builtin_amdgcn_sched_barrier(0);             // issue loads first
        const int o = (jt & 1) << 14;
        const u16 *Kh = lds + o;
        const u16 *Vt = lds + o + 4096;
        const u16 *Ph = lds + o + 8192;

        // ---- score MFMAs
        floatx4 aS[4], aB[5];
#pragma unroll
        for (int i = 0; i < 4; i++) aS[i] = zero;
#pragma unroll
        for (int i = 0; i < 5; i++) aB[i] = zero;
        __builtin_amdgcn_s_setprio(1);
#pragma unroll
        for (int kk = 0; kk < 2; kk++) {
            const int swz = ((((kk << 2) | quad) ^ (l16 & 7)) << 3);
#pragma unroll
            for (int nt = 0; nt < 4; nt++) {
                bf16x8 bf = __builtin_bit_cast(bf16x8,
                    *(const uint4 *)&Kh[(((nt << 4) | l16) << 6) + swz]);
                aS[nt] = __builtin_amdgcn_mfma_f32_16x16x32_bf16(aqu[kk], bf, aS[nt], 0, 0, 0);
            }
#pragma unroll
            for (int rt = 0; rt < 5; rt++) {
                bf16x8 bf = __builtin_bit_cast(bf16x8,
                    *(const uint4 *)&Ph[((((rt + 3 - wv) << 4) | l16) << 6) + swz]);
                aB[rt] = __builtin_amdgcn_mfma_f32_16x16x32_bf16(aqv[kk], bf, aB[rt], 0, 0, 0);
            }
        }
        __builtin_amdgcn_s_setprio(0);

        // ---- assemble S = aS + shfl-remapped bd; no-max softmax; Pb write
#pragma unroll
        for (int e = 0; e < 4; e++) {
            const int r16 = r16q + e;
            const int t = l16 + 15 - r16;          // [0,30]
            const int srcl = (quad << 4) | (t & 15);
            const int carry = t >> 4;
            float ps = 0.f;
#pragma unroll
            for (int nt = 0; nt < 4; nt++) {
                float vlo = __shfl(aB[nt][e], srcl, 64);
                float vhi = __shfl(aB[nt + 1][e], srcl, 64);
                float bd = carry ? vhi : vlo;
                float pe = __expf(aS[nt][e] + bd);
                ps += pe;
                Pb[(((wv << 4) + r16) * 72) + (nt << 4) + l16] = f2b(pe);
            }
            lacc[e] += ps;
        }
        // Pb rows are wave-private: in-wave RAW handled by lgkmcnt, no barrier.

        // ---- PV MFMAs: accO += P(16x64) x V(64x64)
        __builtin_amdgcn_s_setprio(1);
#pragma unroll
        for (int kk = 0; kk < 2; kk++) {
            const int swz = ((((kk << 2) | quad) ^ (l16 & 7)) << 3);
            bf16x8 ap = __builtin_bit_cast(bf16x8,
                *(const uint4 *)&Pb[(((wv << 4) | l16) * 72) + (kk << 5) + (quad << 3)]);
#pragma unroll
            for (int nd = 0; nd < 4; nd++) {
                bf16x8 bv = __builtin_bit_cast(bf16x8,
                    *(const uint4 *)&Vt[(((nd << 4) | l16) << 6) + swz]);
                accO[nd] = __builtin_amdgcn_mfma_f32_16x16x32_bf16(ap, bv, accO[nd], 0, 0, 0);
            }
        }
        __builtin_amdgcn_s_setprio(0);

        if (jt + 1 < 16) {
            __builtin_amdgcn_sched_barrier(0);   // reads of buf jt done before barrier
            __builtin_amdgcn_s_barrier();        // all waves done reading buf jt
            asm volatile("s_waitcnt vmcnt(0)" ::: "memory");  // jt+1 loads landed
            __builtin_amdgcn_s_barrier();        // buf jt+1 visible everywhere
            __builtin_amdgcn_sched_barrier(0);
        }
    }

    // ---- epilogue: reduce l across quad (cols), then O/l -> attno (t, b, h*64+d)
    const int b = zg >> 3, h = zg & 7;
#pragma unroll
    for (int e = 0; e < 4; e++) {
#pragma unroll
        for (int msk = 1; msk < 16; msk <<= 1) lacc[e] += __shfl_xor(lacc[e], msk, 64);
        float inv = 1.f / lacc[e];
        int t = i0 + (wv << 4) + (quad << 2) + e;
#pragma unroll
        for (int nd = 0; nd < 4; nd++) {
            int d = (nd << 4) + l16;
            p.attno[(long long)(t * B_ + b) * E_ + h * 64 + d] = f2b(accO[nd][e] * inv);
        }
    }
}

// ---------------- small helper kernels -------------------------------------------

__global__ __launch_bounds__(256) void repack_qkv_k(const u16 *qkv, const u16 *u, const u16 *v,
                                                    u16 *QU, u16 *QV, u16 *KH) {
    int gid = blockIdx.x * 256 + threadIdx.x;  // 32*1024*64 = 2M
    int z = gid >> 16, rem = gid & 65535;
    int t = rem >> 6, d = rem & 63;
    int b = z >> 3, h = z & 7;
    long long base = (long long)(t * B_ + b) * (3 * E_) + h * 64 + d;
    float q = b2f(qkv[base]);
    QU[gid] = f2b(q + b2f(u[h * 64 + d]));
    QV[gid] = f2b(q + b2f(v[h * 64 + d]));
    KH[gid] = qkv[base + E_];
}

__global__ __launch_bounds__(256) void transpose_v_k(const u16 *qkv, u16 *VT) {
    __shared__ u16 lds[64 * 65];
    int z = blockIdx.y, t0 = blockIdx.x * 64;
    int b = z >> 3, h = z & 7;
    int tid = threadIdx.x, wv = tid >> 6, ln = tid & 63;
    for (int rr = 0; rr < 16; rr++) {
        int tl = wv * 16 + rr;
        lds[ln * 65 + tl] = qkv[(long long)((t0 + tl) * B_ + b) * (3 * E_) + 2 * E_ + h * 64 + ln];
    }
    __syncthreads();
    int d = tid >> 2, seg = tid & 3;
    long long ob = (long long)(z * 64 + d) * T_ + t0 + seg * 16;
    for (int ii = 0; ii < 16; ii++) VT[ob + ii] = lds[d * 65 + seg * 16 + ii];
}

__global__ __launch_bounds__(256) void glu_k(const u16 *y1, u16 *ch) {
    int gid = blockIdx.x * 256 + threadIdx.x;  // 4096*512
    int r = gid >> 9, c = gid & 511;
    float a = b2f(y1[(long long)r * (2 * E_) + c]);
    float g = b2f(y1[(long long)r * (2 * E_) + E_ + c]);
    ch[gid] = f2b(a * (1.f / (1.f + __expf(-g))));
}

// depthwise conv — register sliding window. Thread = (b, channel-pair) x 8 t's.
__global__ __launch_bounds__(256) void dwconv_k(const u16 *ch, const u16 *w, const u16 *bias,
                                                u16 *cd) {
    const int cp = threadIdx.x;
    const int b = blockIdx.x >> 7;
    const int t0 = (blockIdx.x & 127) << 3;
    const int c0 = cp << 1;
    float in0[38], in1[38];
#pragma unroll
    for (int j = 0; j < 38; j++) {
        int tt = t0 - 15 + j;
        u32 v = 0;
        if (tt >= 0 && tt < T_) v = *(const u32 *)&ch[tt * 2048 + b * 512 + c0];
        in0[j] = b2f((u16)(v & 0xffff));
        in1[j] = b2f((u16)(v >> 16));
    }
    float w0[KW_], w1[KW_];
#pragma unroll
    for (int kk = 0; kk < KW_; kk++) {
        w0[kk] = b2f(w[c0 * KW_ + kk]);
        w1[kk] = b2f(w[c0 * KW_ + KW_ + kk]);
    }
    float bi0 = b2f(bias[c0]), bi1 = b2f(bias[c0 + 1]);
#pragma unroll
    for (int t = 0; t < 8; t++) {
        float a0 = bi0, a1 = bi1;
#pragma unroll
        for (int kk = 0; kk < KW_; kk++) {
            a0 += in0[t + kk] * w0[kk];
            a1 += in1[t + kk] * w1[kk];
        }
        float s0 = 1.f / (1.f + __expf(1.f - a0));
        float s1 = 1.f / (1.f + __expf(1.f - a1));
        u32 o = (u32)f2b(a0 * s0) | ((u32)f2b(a1 * s1) << 16);
        *(u32 *)&cd[(t0 + t) * 2048 + b * 512 + c0] = o;
    }
}

// BasicNorm -> FLOAT32 output. One wave per row.
__global__ __launch_bounds__(256) void norm_k(const float *xr, const float *epsp, float *out) {
    int wv = threadIdx.x >> 6, ln = threadIdx.x & 63;
    long long row = blockIdx.x * 4 + wv;
    const float *x = xr + row * E_;
    float vals[8], ss = 0.f;
#pragma unroll
    for (int i = 0; i < 8; i++) {
        vals[i] = x[ln + (i << 6)];
        ss += vals[i] * vals[i];
    }
#pragma unroll
    for (int m = 32; m; m >>= 1) ss += __shfl_xor(ss, m, 64);
    float sc = rsqrtf(ss * (1.f / (float)E_) + __expf(epsp[0]));
    float *o = out + row * E_;
#pragma unroll
    for (int i = 0; i < 8; i++) o[ln + (i << 6)] = vals[i] * sc;
}

// ---------------- host ------------------------------------------------------------

extern "C" void kernel_launch(void *const *d_in, const int *in_sizes, int n_in,
                              void *d_out, int out_size, void *d_ws, size_t ws_size,
                              hipStream_t stream) {
    const size_t MB = (size_t)1 << 20;
    static const long long EXPECT[24] = {
        2097152, 1048064, 786432, 1536, 262144, 512, 262144, 512, 512,
        1048576, 2048, 1048576, 512, 1048576, 2048, 1048576, 512,
        524288, 1024, 15872, 512, 262144, 512, 1};
    const size_t NEED = 93 * MB;

    float code = 0.f;
    if (n_in != 24) {
        code = 1000.f + (float)n_in;
    } else {
        for (int i = 0; i < 24; i++) {
            if ((long long)in_sizes[i] != EXPECT[i]) { code = 2000.f + 64.f * i; break; }
        }
    }
    if (code == 0.f && out_size != 2097152) code = 3000.f;
    if (code == 0.f && ws_size < NEED) code = 5000.f + (float)(ws_size / MB);
    if (code != 0.f) {
        long long n = (long long)out_size;
        fill_k<<<dim3((unsigned)((n + 255) / 256)), dim3(256), 0, stream>>>((float *)d_out, n, code);
        return;
    }

    char *w = (char *)d_ws;
    int *flag = (int *)(w + 0);
    u16 *cv = (u16 *)(w + 1 * MB);
    float *xr = (float *)(w + 21 * MB);
    u16 *xb = (u16 *)(w + 29 * MB);
    u16 *h1 = (u16 *)(w + 33 * MB);
    u16 *qkv = (u16 *)(w + 49 * MB);
    u16 *y1 = (u16 *)(w + 49 * MB);
    u16 *pph = (u16 *)(w + 63 * MB);
    u16 *QU = (u16 *)(w + 65 * MB);
    u16 *QV = (u16 *)(w + 69 * MB);
    u16 *KH = (u16 *)(w + 73 * MB);
    u16 *VT = (u16 *)(w + 77 * MB);
    u16 *attno = (u16 *)(w + 81 * MB);
    u16 *ch = (u16 *)(w + 85 * MB);
    u16 *cd = (u16 *)(w + 89 * MB);

    detect_k<<<dim3(1), dim3(256), 0, stream>>>((const u16 *)d_in[0], flag);
    CVT c;
    c.pre[0] = 0;
    for (int i = 0; i < 24; i++) {
        c.in[i] = d_in[i];
        c.pre[i + 1] = c.pre[i] + in_sizes[i];
    }
    long long total = c.pre[24];
    convert_k<<<dim3((unsigned)((total + 255) / 256)), dim3(256), 0, stream>>>(c, cv, flag, total);

    const u16 *src = cv + c.pre[0];
    const u16 *pos_emb = cv + c.pre[1];
    const u16 *w_qkv = cv + c.pre[2];
    const u16 *b_qkv = cv + c.pre[3];
    const u16 *w_o = cv + c.pre[4];
    const u16 *b_o = cv + c.pre[5];
    const u16 *w_pos = cv + c.pre[6];
    const u16 *u_bias = cv + c.pre[7];
    const u16 *v_bias = cv + c.pre[8];
    const u16 *ffm_w1 = cv + c.pre[9];
    const u16 *ffm_b1 = cv + c.pre[10];
    const u16 *ffm_w2 = cv + c.pre[11];
    const u16 *ffm_b2 = cv + c.pre[12];
    const u16 *ff_w1 = cv + c.pre[13];
    const u16 *ff_b1 = cv + c.pre[14];
    const u16 *ff_w2 = cv + c.pre[15];
    const u16 *ff_b2 = cv + c.pre[16];
    const u16 *pw1_w = cv + c.pre[17];
    const u16 *pw1_b = cv + c.pre[18];
    const u16 *dw_w = cv + c.pre[19];
    const u16 *dw_b = cv + c.pre[20];
    const u16 *pw2_w = cv + c.pre[21];
    const u16 *pw2_b = cv + c.pre[22];

    auto mk = [](const void *A, int lda, const void *B, int ldb, void *C, int ldc,
                 const void *bias, int M, int N, int K, int mode) {
        GP p;
        memset(&p, 0, sizeof(p));
        p.A = (const u16 *)A; p.B = (const u16 *)B; p.C = (u16 *)C; p.bias = (const u16 *)bias;
        p.M = M; p.N = N; p.K = K; p.lda = lda; p.ldb = ldb; p.ldc = ldc; p.mode = mode;
        p.qscale = 1.f;
        return p;
    };
    auto launch = [&](GP p) {
        dim3 g((p.N + 63) / 64, (p.M + 63) / 64, 1);
        gemm_nt<<<g, dim3(256), 0, stream>>>(p);
    };
    auto launch128 = [&](GP p) {
        dim3 g(p.N >> 7, p.M >> 7, 1);
        gemm_nt128<<<g, dim3(256), 0, stream>>>(p);
    };

    const int M = T_ * B_;  // 4096

    // ---- macaron FFN: x1 = src + W2 @ dswish(W1 @ src + b1) + b2
    { GP p = mk(src, E_, ffm_w1, E_, h1, DFF_, ffm_b1, M, DFF_, E_, 1); launch128(p); }
    { GP p = mk(h1, DFF_, ffm_w2, DFF_, nullptr, E_, ffm_b2, M, E_, DFF_, 2);
      p.resin = d_in[0]; p.resin_f32 = 1; p.xr = xr; p.xb = xb; launch(p); }

    // ---- attention projections
    { GP p = mk(xb, E_, w_qkv, E_, qkv, 3 * E_, b_qkv, M, 3 * E_, E_, 0);
      p.qcols = E_; p.qscale = 0.125f; launch128(p); }
    // pos GEMM writes pph directly (mode 3, fused repack + zero pad row 2047)
    { GP p = mk(pos_emb, E_, w_pos, E_, pph, E_, nullptr, 2 * T_ - 1, E_, E_, 3); launch(p); }
    repack_qkv_k<<<dim3(8192), dim3(256), 0, stream>>>(qkv, u_bias, v_bias, QU, QV, KH);
    transpose_v_k<<<dim3(16, 32), dim3(256), 0, stream>>>(qkv, VT);

    // ---- flash attention (no S materialization)
    {
        FK f;
        f.QU = QU; f.QV = QV; f.KH = KH; f.PPH = pph; f.VT = VT; f.attno = attno;
        flash_k<<<dim3(16, 32), dim3(256), 0, stream>>>(f);
    }

    // ---- out projection + residual -> x2
    { GP p = mk(attno, E_, w_o, E_, nullptr, E_, b_o, M, E_, E_, 2);
      p.resin = xr; p.resin_f32 = 1; p.xr = xr; p.xb = xb; launch(p); }

    // ---- conv module
    { GP p = mk(xb, E_, pw1_w, E_, y1, 2 * E_, pw1_b, M, 2 * E_, E_, 0); launch128(p); }
    glu_k<<<dim3(8192), dim3(256), 0, stream>>>(y1, ch);
    dwconv_k<<<dim3(512), dim3(256), 0, stream>>>(ch, dw_w, dw_b, cd);
    { GP p = mk(cd, E_, pw2_w, E_, nullptr, E_, pw2_b, M, E_, E_, 2);
      p.resin = xr; p.resin_f32 = 1; p.xr = xr; p.xb = xb; launch(p); }

    // ---- second FFN
    { GP p = mk(xb, E_, ff_w1, E_, h1, DFF_, ff_b1, M, DFF_, E_, 1); launch128(p); }
    { GP p = mk(h1, DFF_, ff_w2, DFF_, nullptr, E_, ff_b2, M, E_, DFF_, 2);
      p.resin = xr; p.resin_f32 = 1; p.xr = xr; p.xb = nullptr; launch(p); }

    // ---- final BasicNorm -> d_out (FLOAT32)
    norm_k<<<dim3(M / 4), dim3(256), 0, stream>>>(xr, (const float *)d_in[23], (float *)d_out);
}

// Round 3
// 427.716 us; speedup vs baseline: 1.0558x; 1.0466x over previous
//
#include <hip/hip_runtime.h>
#include <string.h>

// Conformer encoder layer, MI355X gfx950 — ROUND 13.
// R12: 448 us. flash FETCH 45->12MB (XCD swizzle works; L2-resident) but
// still 42us (dep-stalled, 2 waves/SIMD). No kernel >42us: aggregate GEMM
// (~200us) + helpers + fixed 42us harness fill dominate.
// Changes: GEMMs -> 4-buffer pipeline (3 compute phases of slack,
// vmcnt(12/8/4/0)) + XCD-swizzled grids (per-XCD L2 panel reuse). qkv GEMM
// epilogue fused: writes QU/QV/KH/VT directly (repack_qkv + transpose_v
// dispatches removed, -28MB traffic). New gemm_glu: computes both GLU
// halves, writes ch directly (glu_k + y1 removed, -20MB). 18 -> 15
// dispatches. flash_k unchanged. Workspace: 93 MB.

#define T_ 1024
#define B_ 4
#define E_ 512
#define H_ 8
#define DFF_ 2048
#define KW_ 31

typedef unsigned short u16;
typedef unsigned int u32;
typedef __bf16 bf16x8 __attribute__((ext_vector_type(8)));
typedef float floatx4 __attribute__((ext_vector_type(4)));

__device__ __forceinline__ float b2f(u16 u) {
    return __uint_as_float(((u32)u) << 16);
}
__device__ __forceinline__ u16 f2b(float f) {
    u32 i = __float_as_uint(f);
    u32 r = (i + 0x7fffu + ((i >> 16) & 1u)) >> 16;  // RNE, finite inputs only
    return (u16)r;
}

__device__ __forceinline__ void glds16(const u16 *g, u16 *l) {
    __builtin_amdgcn_global_load_lds((const __attribute__((address_space(1))) void *)g,
                                     (__attribute__((address_space(3))) void *)l, 16, 0, 0);
}

// ---------------- diagnostic fill (f32 out) ---------------------------------------
__global__ __launch_bounds__(256) void fill_k(float *out, long long n, float val) {
    long long g = (long long)blockIdx.x * 256 + threadIdx.x;
    if (g < n) out[g] = val;
}

// ---------------- input dtype detect + convert ------------------------------------
__global__ __launch_bounds__(256) void detect_k(const u16 *src16, int *flag) {
    __shared__ int sh[256];
    int tid = threadIdx.x;
    int cnt = 0;
    for (int i = tid; i < 4096; i += 256) {
        u16 x = src16[2 * i];
        int e = (x >> 7) & 0xFF;
        cnt += (e == 0 || (e >= 0x70 && e <= 0x8F)) ? 1 : 0;
    }
    sh[tid] = cnt;
    __syncthreads();
    for (int s = 128; s; s >>= 1) {
        if (tid < s) sh[tid] += sh[tid + s];
        __syncthreads();
    }
    if (tid == 0) *flag = (sh[0] < 2048) ? 1 : 0;  // 1 = f32 inputs, 0 = bf16
}

struct CVT {
    const void *in[24];
    long long pre[25];
};

__global__ __launch_bounds__(256) void convert_k(CVT c, u16 *dst, const int *flag,
                                                 long long total) {
    long long g = (long long)blockIdx.x * 256 + threadIdx.x;
    if (g >= total) return;
    int s = 0;
#pragma unroll
    for (int i = 1; i < 25; i++) s += (g >= c.pre[i]) ? 1 : 0;
    long long l = g - c.pre[s];
    int f = *flag;
    u16 v = f ? f2b(((const float *)c.in[s])[l]) : ((const u16 *)c.in[s])[l];
    dst[g] = v;
}

// ---------------- generic NT GEMM: C(M,N) = A(M,K) @ B(N,K)^T ----------------------
struct GP {
    const u16 *A, *B;
    u16 *C;
    const u16 *bias;
    const void *resin;     // mode 2: residual input (bf16 or f32)
    float *xr;             // mode 2: f32 residual out
    u16 *xb;               // mode 2: bf16 copy out (may be null)
    const u16 *ub, *vb;    // mode 4: u/v biases
    u16 *qu, *qv, *kh, *vt;  // mode 4: fused qkv repack outputs
    int M, N, K, lda, ldb, ldc, mode, qcols, resin_f32;
    float qscale;
};

// 64x64 tile, BK=64, glds16 staging w/ XOR swizzle (conflict-free b128 reads).
// R13: 4-buffer pipeline (3 compute phases of slack), vmcnt(12/8/4/0),
// XCD-swizzled grid. modes: 0 bf16; 1 DoubleSwish; 2 residual; 3 pph repack.
__global__ __launch_bounds__(256) void gemm_nt(GP p) {
    __shared__ __align__(16) u16 As[4 * 4096];
    __shared__ __align__(16) u16 Bs[4 * 4096];
    const int tid = threadIdx.x;
    const int wv = tid >> 6, ln = tid & 63;
    const int l16 = ln & 15, quad = ln >> 4;
    // XCD swizzle: grid.x*grid.y % 8 == 0 at every call site (bijective)
    const int gx = gridDim.x;
    const int nb = gx * gridDim.y;
    const int lid = blockIdx.y * gx + blockIdx.x;
    const int nid = (lid & 7) * (nb >> 3) + (lid >> 3);
    const int m0 = (nid / gx) << 6, n0 = (nid % gx) << 6;
    floatx4 zero = {0.f, 0.f, 0.f, 0.f};
    floatx4 acc[4];
#pragma unroll
    for (int i = 0; i < 4; i++) acc[i] = zero;

    const int NT = p.K >> 6;  // BK=64; all call-site K >= 512 -> NT >= 8

    // stage = 4 glds16 per thread (A x2, B x2). Row-clamped A: no divergence,
    // uniform per-wave vmcnt count. Clamped rows masked at store.
    auto stage = [&](int bidx, int t) {
        const int k0 = t << 6;
        const int o = bidx << 12;  // 4096 u16 per buffer
#pragma unroll
        for (int ps = 0; ps < 2; ps++) {
            int g = ps * 256 + tid;
            int row = g >> 3;
            int src = ((g & 7) ^ (row & 7)) << 3;
            int ra = m0 + row;
            if (ra > p.M - 1) ra = p.M - 1;
            glds16(p.A + (long long)ra * p.lda + k0 + src, As + o + g * 8);
            glds16(p.B + (long long)(n0 + row) * p.ldb + k0 + src, Bs + o + g * 8);
        }
    };

    stage(0, 0);
    stage(1, 1);
    stage(2, 2);
    stage(3, 3);
    asm volatile("s_waitcnt vmcnt(12)" ::: "memory");  // buf0's 4 loads done
    __builtin_amdgcn_s_barrier();

    int cb = 0;  // t % 4
    for (int t = 0; t < NT; t++) {
        const int o = cb << 12;
#pragma unroll
        for (int kk = 0; kk < 2; kk++) {
            const int swz = ((((kk << 2) | quad) ^ (l16 & 7)) << 3);
            bf16x8 af = __builtin_bit_cast(bf16x8,
                *(const uint4 *)&As[o + (((wv << 4) | l16) << 6) + swz]);
#pragma unroll
            for (int nt = 0; nt < 4; nt++) {
                bf16x8 bf = __builtin_bit_cast(bf16x8,
                    *(const uint4 *)&Bs[o + (((nt << 4) | l16) << 6) + swz]);
                acc[nt] = __builtin_amdgcn_mfma_f32_16x16x32_bf16(af, bf, acc[nt], 0, 0, 0);
            }
        }
        if (t + 1 < NT) {
            __builtin_amdgcn_sched_barrier(0);   // reads of buf complete before barrier
            __builtin_amdgcn_s_barrier();        // all waves done reading buf t
            if (t + 4 < NT) {
                stage(cb, t + 4);                // re-stage retired buffer
                asm volatile("s_waitcnt vmcnt(12)" ::: "memory");  // buf t+1 done
            } else if (t + 3 < NT) {
                asm volatile("s_waitcnt vmcnt(8)" ::: "memory");
            } else if (t + 2 < NT) {
                asm volatile("s_waitcnt vmcnt(4)" ::: "memory");
            } else {
                asm volatile("s_waitcnt vmcnt(0)" ::: "memory");
            }
            __builtin_amdgcn_s_barrier();        // buf t+1 visible everywhere
            __builtin_amdgcn_sched_barrier(0);   // no hoisting of next reads above this
        }
        cb = (cb + 1) & 3;
    }

#pragma unroll
    for (int nt = 0; nt < 4; nt++) {
#pragma unroll
        for (int r = 0; r < 4; r++) {
            int gr = m0 + (wv << 4) + (quad << 2) + r;
            int gc = n0 + (nt << 4) + l16;
            bool oob = gr >= p.M;
            if (oob && p.mode != 3) continue;
            float y = 0.f;
            if (!oob) {
                y = acc[nt][r];
                if (p.bias) y += b2f(p.bias[gc]);
                if (gc < p.qcols) y *= p.qscale;
            }
            if (p.mode == 3) {
                // fused repack_pos: C = pph, layout [(h*2048 + m)*64 + d]
                p.C[((gc >> 6) << 17) + (gr << 6) + (gc & 63)] = f2b(y);
            } else if (p.mode == 0) {
                p.C[(long long)gr * p.ldc + gc] = f2b(y);
            } else if (p.mode == 1) {
                float s = 1.f / (1.f + __expf(1.f - y));  // x*sigmoid(x-1)
                p.C[(long long)gr * p.ldc + gc] = f2b(y * s);
            } else {  // mode 2
                long long idx = (long long)gr * p.ldc + gc;
                float rv = p.resin_f32 ? ((const float *)p.resin)[idx]
                                       : b2f(((const u16 *)p.resin)[idx]);
                float o = rv + y;
                p.xr[idx] = o;
                if (p.xb) p.xb[idx] = f2b(o);
            }
        }
    }
}

// ---------------- 128x128 m97-style GEMM (z=1, M%128==0, N%128==0, K%32==0) --------
// XOR swizzle on 4-granule rows kills the 8-way read conflicts.
// R13: 4-buffer pipeline, vmcnt(12/8/4/0), XCD swizzle, mode 4 = fused qkv.
__global__ __launch_bounds__(256) void gemm_nt128(GP p) {
    __shared__ __align__(16) u16 As[4 * 4096];
    __shared__ __align__(16) u16 Bs[4 * 4096];
    const int tid = threadIdx.x;
    const int wv = tid >> 6, ln = tid & 63;
    const int l16 = ln & 15, quad = ln >> 4;
    const int wm = (wv >> 1) << 6, wn = (wv & 1) << 6;
    // XCD swizzle (grid.x*grid.y % 8 == 0 at every call site)
    const int gx = gridDim.x;
    const int nb = gx * gridDim.y;
    const int lid = blockIdx.y * gx + blockIdx.x;
    const int nid = (lid & 7) * (nb >> 3) + (lid >> 3);
    const int m0 = (nid / gx) << 7, n0 = (nid % gx) << 7;
    const int srow = ln >> 2;
    const int scol = (((ln & 3) ^ ((ln >> 3) & 3)) << 3);  // swizzled source granule
    const u16 *Ag1 = p.A + (long long)(m0 + (wv << 4) + srow) * p.lda + scol;
    const u16 *Ag2 = Ag1 + (long long)64 * p.lda;
    const u16 *Bg1 = p.B + (long long)(n0 + (wv << 4) + srow) * p.ldb + scol;
    const u16 *Bg2 = Bg1 + (long long)64 * p.ldb;
    u16 *Al1 = &As[(wv << 4) << 5];
    u16 *Al2 = &As[((wv << 4) + 64) << 5];
    u16 *Bl1 = &Bs[(wv << 4) << 5];
    u16 *Bl2 = &Bs[((wv << 4) + 64) << 5];
    floatx4 zero = {0.f, 0.f, 0.f, 0.f};
    floatx4 acc[4][4];
#pragma unroll
    for (int i = 0; i < 4; i++)
#pragma unroll
        for (int j = 0; j < 4; j++) acc[i][j] = zero;

    const int rswz = ((quad ^ ((l16 >> 1) & 3)) << 3);  // read-side swizzle
    const int NT = p.K >> 5;  // BK=32; K>=512 -> NT>=16

    auto stage = [&](int bidx, int t) {  // 4 glds16 per thread
        const int k0 = t << 5;
        const int o = bidx << 12;  // 4096 u16 per buffer
        glds16(Ag1 + k0, Al1 + o);
        glds16(Ag2 + k0, Al2 + o);
        glds16(Bg1 + k0, Bl1 + o);
        glds16(Bg2 + k0, Bl2 + o);
    };

    stage(0, 0);
    stage(1, 1);
    stage(2, 2);
    stage(3, 3);
    asm volatile("s_waitcnt vmcnt(12)" ::: "memory");  // buf0's 4 loads done
    __builtin_amdgcn_s_barrier();

    int cb = 0;  // t % 4
    for (int t = 0; t < NT; t++) {
        const int o = cb << 12;
        bf16x8 av[4], bv[4];
#pragma unroll
        for (int mt = 0; mt < 4; mt++)
            av[mt] = __builtin_bit_cast(bf16x8,
                *(const uint4 *)&As[o + ((wm + (mt << 4) + l16) << 5) + rswz]);
#pragma unroll
        for (int nt = 0; nt < 4; nt++)
            bv[nt] = __builtin_bit_cast(bf16x8,
                *(const uint4 *)&Bs[o + ((wn + (nt << 4) + l16) << 5) + rswz]);
#pragma unroll
        for (int mt = 0; mt < 4; mt++)
#pragma unroll
            for (int nt = 0; nt < 4; nt++)
                acc[mt][nt] = __builtin_amdgcn_mfma_f32_16x16x32_bf16(av[mt], bv[nt],
                                                                      acc[mt][nt], 0, 0, 0);
        if (t + 1 < NT) {
            __builtin_amdgcn_sched_barrier(0);   // reads of buf complete before barrier
            __builtin_amdgcn_s_barrier();        // all waves done reading buf t
            if (t + 4 < NT) {
                stage(cb, t + 4);                // re-stage retired buffer
                asm volatile("s_waitcnt vmcnt(12)" ::: "memory");  // buf t+1 done
            } else if (t + 3 < NT) {
                asm volatile("s_waitcnt vmcnt(8)" ::: "memory");
            } else if (t + 2 < NT) {
                asm volatile("s_waitcnt vmcnt(4)" ::: "memory");
            } else {
                asm volatile("s_waitcnt vmcnt(0)" ::: "memory");
            }
            __builtin_amdgcn_s_barrier();        // buf t+1 visible everywhere
            __builtin_amdgcn_sched_barrier(0);   // no hoisting of next reads above this
        }
        cb = (cb + 1) & 3;
    }

#pragma unroll
    for (int mt = 0; mt < 4; mt++)
#pragma unroll
        for (int nt = 0; nt < 4; nt++)
#pragma unroll
            for (int r = 0; r < 4; r++) {
                int gr = m0 + wm + (mt << 4) + (quad << 2) + r;
                int gc = n0 + wn + (nt << 4) + l16;
                float y = acc[mt][nt][r];
                if (p.bias) y += b2f(p.bias[gc]);
                if (gc < p.qcols) y *= p.qscale;
                if (p.mode == 0) {
                    p.C[(long long)gr * p.ldc + gc] = f2b(y);
                } else if (p.mode == 1) {
                    float s = 1.f / (1.f + __expf(1.f - y));
                    p.C[(long long)gr * p.ldc + gc] = f2b(y * s);
                } else if (p.mode == 4) {
                    // fused qkv repack: rows are (t,b) pairs, b fastest
                    int t = gr >> 2, b = gr & 3;
                    if (gc < E_) {  // Q -> QU/QV with u/v biases (y already scaled)
                        int z = b * 8 + (gc >> 6);
                        long long oq = ((long long)z << 16) + (t << 6) + (gc & 63);
                        p.qu[oq] = f2b(y + b2f(p.ub[gc]));
                        p.qv[oq] = f2b(y + b2f(p.vb[gc]));
                    } else if (gc < 2 * E_) {  // K -> KH [z][t][d]
                        int c = gc - E_;
                        int z = b * 8 + (c >> 6);
                        p.kh[((long long)z << 16) + (t << 6) + (c & 63)] = f2b(y);
                    } else {  // V -> VT [z*64+d][t] (transposed)
                        int c = gc - 2 * E_;
                        int z = b * 8 + (c >> 6);
                        p.vt[(long long)((z << 6) + (c & 63)) * T_ + t] = f2b(y);
                    }
                } else {  // mode 2
                    long long idx = (long long)gr * p.ldc + gc;
                    float rv = p.resin_f32 ? ((const float *)p.resin)[idx]
                                           : b2f(((const u16 *)p.resin)[idx]);
                    float o = rv + y;
                    p.xr[idx] = o;
                    if (p.xb) p.xb[idx] = f2b(o);
                }
            }
}

// ---------------- fused pw1 + GLU: ch(M,512) = GLU(A @ W^T + b) --------------------
// Block computes 64x64 of BOTH halves (a-cols n0.., g-cols 512+n0..) then
// writes ch = a * sigmoid(g) directly. 3-buffer pipeline, 6 loads/stage.
__global__ __launch_bounds__(256) void gemm_glu(const u16 *A, const u16 *W, const u16 *bias,
                                                u16 *ch) {
    __shared__ __align__(16) u16 As[3 * 4096];
    __shared__ __align__(16) u16 Ba[3 * 4096];
    __shared__ __align__(16) u16 Bg[3 * 4096];
    const int tid = threadIdx.x;
    const int wv = tid >> 6, ln = tid & 63;
    const int l16 = ln & 15, quad = ln >> 4;
    const int gx = gridDim.x;  // 8
    const int nb = gx * gridDim.y;  // 512
    const int lid = blockIdx.y * gx + blockIdx.x;
    const int nid = (lid & 7) * (nb >> 3) + (lid >> 3);
    const int m0 = (nid / gx) << 6, n0 = (nid % gx) << 6;
    floatx4 zero = {0.f, 0.f, 0.f, 0.f};
    floatx4 aa[4], ag[4];
#pragma unroll
    for (int i = 0; i < 4; i++) { aa[i] = zero; ag[i] = zero; }

    const int NT = 8;  // K=512, BK=64

    auto stage = [&](int bidx, int t) {  // 6 glds16 per thread
        const int k0 = t << 6;
        const int o = bidx << 12;
#pragma unroll
        for (int ps = 0; ps < 2; ps++) {
            int g = ps * 256 + tid;
            int row = g >> 3;
            int src = ((g & 7) ^ (row & 7)) << 3;
            glds16(A + ((m0 + row) << 9) + k0 + src, As + o + g * 8);
            glds16(W + ((n0 + row) << 9) + k0 + src, Ba + o + g * 8);
            glds16(W + ((E_ + n0 + row) << 9) + k0 + src, Bg + o + g * 8);
        }
    };

    stage(0, 0);
    stage(1, 1);
    stage(2, 2);
    asm volatile("s_waitcnt vmcnt(12)" ::: "memory");  // buf0's 6 loads done
    __builtin_amdgcn_s_barrier();

    int cb = 0;
    for (int t = 0; t < NT; t++) {
        const int o = cb << 12;
#pragma unroll
        for (int kk = 0; kk < 2; kk++) {
            const int swz = ((((kk << 2) | quad) ^ (l16 & 7)) << 3);
            bf16x8 af = __builtin_bit_cast(bf16x8,
                *(const uint4 *)&As[o + (((wv << 4) | l16) << 6) + swz]);
#pragma unroll
            for (int nt = 0; nt < 4; nt++) {
                bf16x8 bfa = __builtin_bit_cast(bf16x8,
                    *(const uint4 *)&Ba[o + (((nt << 4) | l16) << 6) + swz]);
                aa[nt] = __builtin_amdgcn_mfma_f32_16x16x32_bf16(af, bfa, aa[nt], 0, 0, 0);
                bf16x8 bfg = __builtin_bit_cast(bf16x8,
                    *(const uint4 *)&Bg[o + (((nt << 4) | l16) << 6) + swz]);
                ag[nt] = __builtin_amdgcn_mfma_f32_16x16x32_bf16(af, bfg, ag[nt], 0, 0, 0);
            }
        }
        if (t + 1 < NT) {
            __builtin_amdgcn_sched_barrier(0);
            __builtin_amdgcn_s_barrier();
            if (t + 3 < NT) {
                stage(cb, t + 3);
                asm volatile("s_waitcnt vmcnt(12)" ::: "memory");
            } else if (t + 2 < NT) {
                asm volatile("s_waitcnt vmcnt(6)" ::: "memory");
            } else {
                asm volatile("s_waitcnt vmcnt(0)" ::: "memory");
            }
            __builtin_amdgcn_s_barrier();
            __builtin_amdgcn_sched_barrier(0);
        }
        cb = (cb == 2) ? 0 : cb + 1;
    }

#pragma unroll
    for (int nt = 0; nt < 4; nt++) {
#pragma unroll
        for (int r = 0; r < 4; r++) {
            int gr = m0 + (wv << 4) + (quad << 2) + r;
            int gc = n0 + (nt << 4) + l16;
            float a = aa[nt][r] + b2f(bias[gc]);
            float g = ag[nt][r] + b2f(bias[E_ + gc]);
            ch[((long long)gr << 9) + gc] = f2b(a * (1.f / (1.f + __expf(-g))));
        }
    }
}

// ---------------- flash attention v3 (unchanged from R12) --------------------------
struct FK {
    const u16 *QU, *QV, *KH, *PPH, *VT;
    u16 *attno;
};

__global__ __launch_bounds__(256) void flash_k(FK p) {
    // per-buffer (16384 u16): Kh [0,4096) 64x64 | Vt [4096,8192) 64x64 |
    // Ph [8192,16384) 128x64. Pb at 32768: 64x72 (padded, per-lane stores).
    __shared__ __align__(16) u16 lds[2 * 16384 + 4608];  // 73 KB

    const int tid = threadIdx.x;
    const int wv = tid >> 6, ln = tid & 63;
    const int l16 = ln & 15, quad = ln >> 4;
    const int lid = blockIdx.y * 16 + blockIdx.x;
    const int nid = (lid & 7) * 64 + (lid >> 3);  // XCD-cluster swizzle (bijective)
    const int zg = nid >> 4;
    const int i0 = (nid & 15) << 6;
    const u16 *kh0 = p.KH + (long long)zg * 65536;
    const u16 *ph0 = p.PPH + (long long)(zg & 7) * 131072;
    const u16 *vt0 = p.VT + (long long)zg * 65536;
    u16 *Pb = lds + 32768;

    auto stage = [&](int buf, int jt) {  // 8 glds16 per thread
        const int j0 = jt << 6;
        const int m_start = 960 - i0 + j0;  // [0,1920]; +127 <= 2047 (pph pad row)
        u16 *Kh = lds + (buf << 14);
        u16 *Vt = Kh + 4096;
        u16 *Ph = Kh + 8192;
#pragma unroll
        for (int ps = 0; ps < 2; ps++) {
            int g = ps * 256 + tid;
            int row = g >> 3;
            int src = ((g & 7) ^ (row & 7)) << 3;
            glds16(kh0 + ((j0 + row) << 6) + src, Kh + g * 8);
            glds16(vt0 + (row << 10) + j0 + src, Vt + g * 8);
        }
#pragma unroll
        for (int ps = 0; ps < 4; ps++) {
            int g = ps * 256 + tid;
            int row = g >> 3;
            int src = ((g & 7) ^ (row & 7)) << 3;
            glds16(ph0 + ((m_start + row) << 6) + src, Ph + g * 8);
        }
    };

    // Q fragments from global into registers (A-layout: row l16, k quad*8+kk*32)
    const long long qoff = (long long)zg * 65536 + (long long)(i0 + (wv << 4) + l16) * 64 + (quad << 3);
    bf16x8 aqu[2], aqv[2];
#pragma unroll
    for (int kk = 0; kk < 2; kk++) {
        aqu[kk] = __builtin_bit_cast(bf16x8, *(const uint4 *)(p.QU + qoff + (kk << 5)));
        aqv[kk] = __builtin_bit_cast(bf16x8, *(const uint4 *)(p.QV + qoff + (kk << 5)));
    }

    stage(0, 0);
    asm volatile("s_waitcnt vmcnt(0)" ::: "memory");  // buf0 staged (+ Q loads done)
    __builtin_amdgcn_s_barrier();

    float lacc[4];
    floatx4 accO[4];
    floatx4 zero = {0.f, 0.f, 0.f, 0.f};
#pragma unroll
    for (int e = 0; e < 4; e++) lacc[e] = 0.f;
#pragma unroll
    for (int i = 0; i < 4; i++) accO[i] = zero;

    const int r16q = quad << 2;  // r16 base for this lane's quad

    for (int jt = 0; jt < 16; jt++) {
        if (jt + 1 < 16) stage((jt + 1) & 1, jt + 1);  // prefetch under compute
        __builtin_amdgcn_sched_barrier(0);             // issue loads first
        const int o = (jt & 1) << 14;
        const u16 *Kh = lds + o;
        const u16 *Vt = lds + o + 4096;
        const u16 *Ph = lds + o + 8192;

        // ---- score MFMAs
        floatx4 aS[4], aB[5];
#pragma unroll
        for (int i = 0; i < 4; i++) aS[i] = zero;
#pragma unroll
        for (int i = 0; i < 5; i++) aB[i] = zero;
        __builtin_amdgcn_s_setprio(1);
#pragma unroll
        for (int kk = 0; kk < 2; kk++) {
            const int swz = ((((kk << 2) | quad) ^ (l16 & 7)) << 3);
#pragma unroll
            for (int nt = 0; nt < 4; nt++) {
                bf16x8 bf = __builtin_bit_cast(bf16x8,
                    *(const uint4 *)&Kh[(((nt << 4) | l16) << 6) + swz]);
                aS[nt] = __builtin_amdgcn_mfma_f32_16x16x32_bf16(aqu[kk], bf, aS[nt], 0, 0, 0);
            }
#pragma unroll
            for (int rt = 0; rt < 5; rt++) {
                bf16x8 bf = __builtin_bit_cast(bf16x8,
                    *(const uint4 *)&Ph[((((rt + 3 - wv) << 4) | l16) << 6) + swz]);
                aB[rt] = __builtin_amdgcn_mfma_f32_16x16x32_bf16(aqv[kk], bf, aB[rt], 0, 0, 0);
            }
        }
        __builtin_amdgcn_s_setprio(0);

        // ---- assemble S = aS + shfl-remapped bd; no-max softmax; Pb write
#pragma unroll
        for (int e = 0; e < 4; e++) {
            const int r16 = r16q + e;
            const int t = l16 + 15 - r16;          // [0,30]
            const int srcl = (quad << 4) | (t & 15);
            const int carry = t >> 4;
            float ps = 0.f;
#pragma unroll
            for (int nt = 0; nt < 4; nt++) {
                float vlo = __shfl(aB[nt][e], srcl, 64);
                float vhi = __shfl(aB[nt + 1][e], srcl, 64);
                float bd = carry ? vhi : vlo;
                float pe = __expf(aS[nt][e] + bd);
                ps += pe;
                Pb[(((wv << 4) + r16) * 72) + (nt << 4) + l16] = f2b(pe);
            }
            lacc[e] += ps;
        }
        // Pb rows are wave-private: in-wave RAW handled by lgkmcnt, no barrier.

        // ---- PV MFMAs: accO += P(16x64) x V(64x64)
        __builtin_amdgcn_s_setprio(1);
#pragma unroll
        for (int kk = 0; kk < 2; kk++) {
            const int swz = ((((kk << 2) | quad) ^ (l16 & 7)) << 3);
            bf16x8 ap = __builtin_bit_cast(bf16x8,
                *(const uint4 *)&Pb[(((wv << 4) | l16) * 72) + (kk << 5) + (quad << 3)]);
#pragma unroll
            for (int nd = 0; nd < 4; nd++) {
                bf16x8 bv = __builtin_bit_cast(bf16x8,
                    *(const uint4 *)&Vt[(((nd << 4) | l16) << 6) + swz]);
                accO[nd] = __builtin_amdgcn_mfma_f32_16x16x32_bf16(ap, bv, accO[nd], 0, 0, 0);
            }
        }
        __builtin_amdgcn_s_setprio(0);

        if (jt + 1 < 16) {
            __builtin_amdgcn_sched_barrier(0);   // reads of buf jt done before barrier
            __builtin_amdgcn_s_barrier();        // all waves done reading buf jt
            asm volatile("s_waitcnt vmcnt(0)" ::: "memory");  // jt+1 loads landed
            __builtin_amdgcn_s_barrier();        // buf jt+1 visible everywhere
            __builtin_amdgcn_sched_barrier(0);
        }
    }

    // ---- epilogue: reduce l across quad (cols), then O/l -> attno (t, b, h*64+d)
    const int b = zg >> 3, h = zg & 7;
#pragma unroll
    for (int e = 0; e < 4; e++) {
#pragma unroll
        for (int msk = 1; msk < 16; msk <<= 1) lacc[e] += __shfl_xor(lacc[e], msk, 64);
        float inv = 1.f / lacc[e];
        int t = i0 + (wv << 4) + (quad << 2) + e;
#pragma unroll
        for (int nd = 0; nd < 4; nd++) {
            int d = (nd << 4) + l16;
            p.attno[(long long)(t * B_ + b) * E_ + h * 64 + d] = f2b(accO[nd][e] * inv);
        }
    }
}

// ---------------- small helper kernels -------------------------------------------

// depthwise conv — register sliding window. Thread = (b, channel-pair) x 8 t's.
__global__ __launch_bounds__(256) void dwconv_k(const u16 *ch, const u16 *w, const u16 *bias,
                                                u16 *cd) {
    const int cp = threadIdx.x;
    const int b = blockIdx.x >> 7;
    const int t0 = (blockIdx.x & 127) << 3;
    const int c0 = cp << 1;
    float in0[38], in1[38];
#pragma unroll
    for (int j = 0; j < 38; j++) {
        int tt = t0 - 15 + j;
        u32 v = 0;
        if (tt >= 0 && tt < T_) v = *(const u32 *)&ch[tt * 2048 + b * 512 + c0];
        in0[j] = b2f((u16)(v & 0xffff));
        in1[j] = b2f((u16)(v >> 16));
    }
    float w0[KW_], w1[KW_];
#pragma unroll
    for (int kk = 0; kk < KW_; kk++) {
        w0[kk] = b2f(w[c0 * KW_ + kk]);
        w1[kk] = b2f(w[c0 * KW_ + KW_ + kk]);
    }
    float bi0 = b2f(bias[c0]), bi1 = b2f(bias[c0 + 1]);
#pragma unroll
    for (int t = 0; t < 8; t++) {
        float a0 = bi0, a1 = bi1;
#pragma unroll
        for (int kk = 0; kk < KW_; kk++) {
            a0 += in0[t + kk] * w0[kk];
            a1 += in1[t + kk] * w1[kk];
        }
        float s0 = 1.f / (1.f + __expf(1.f - a0));
        float s1 = 1.f / (1.f + __expf(1.f - a1));
        u32 o = (u32)f2b(a0 * s0) | ((u32)f2b(a1 * s1) << 16);
        *(u32 *)&cd[(t0 + t) * 2048 + b * 512 + c0] = o;
    }
}

// BasicNorm -> FLOAT32 output. One wave per row.
__global__ __launch_bounds__(256) void norm_k(const float *xr, const float *epsp, float *out) {
    int wv = threadIdx.x >> 6, ln = threadIdx.x & 63;
    long long row = blockIdx.x * 4 + wv;
    const float *x = xr + row * E_;
    float vals[8], ss = 0.f;
#pragma unroll
    for (int i = 0; i < 8; i++) {
        vals[i] = x[ln + (i << 6)];
        ss += vals[i] * vals[i];
    }
#pragma unroll
    for (int m = 32; m; m >>= 1) ss += __shfl_xor(ss, m, 64);
    float sc = rsqrtf(ss * (1.f / (float)E_) + __expf(epsp[0]));
    float *o = out + row * E_;
#pragma unroll
    for (int i = 0; i < 8; i++) o[ln + (i << 6)] = vals[i] * sc;
}

// ---------------- host ------------------------------------------------------------

extern "C" void kernel_launch(void *const *d_in, const int *in_sizes, int n_in,
                              void *d_out, int out_size, void *d_ws, size_t ws_size,
                              hipStream_t stream) {
    const size_t MB = (size_t)1 << 20;
    static const long long EXPECT[24] = {
        2097152, 1048064, 786432, 1536, 262144, 512, 262144, 512, 512,
        1048576, 2048, 1048576, 512, 1048576, 2048, 1048576, 512,
        524288, 1024, 15872, 512, 262144, 512, 1};
    const size_t NEED = 93 * MB;

    float code = 0.f;
    if (n_in != 24) {
        code = 1000.f + (float)n_in;
    } else {
        for (int i = 0; i < 24; i++) {
            if ((long long)in_sizes[i] != EXPECT[i]) { code = 2000.f + 64.f * i; break; }
        }
    }
    if (code == 0.f && out_size != 2097152) code = 3000.f;
    if (code == 0.f && ws_size < NEED) code = 5000.f + (float)(ws_size / MB);
    if (code != 0.f) {
        long long n = (long long)out_size;
        fill_k<<<dim3((unsigned)((n + 255) / 256)), dim3(256), 0, stream>>>((float *)d_out, n, code);
        return;
    }

    char *w = (char *)d_ws;
    int *flag = (int *)(w + 0);
    u16 *cv = (u16 *)(w + 1 * MB);
    float *xr = (float *)(w + 21 * MB);
    u16 *xb = (u16 *)(w + 29 * MB);
    u16 *h1 = (u16 *)(w + 33 * MB);
    u16 *pph = (u16 *)(w + 63 * MB);
    u16 *QU = (u16 *)(w + 65 * MB);
    u16 *QV = (u16 *)(w + 69 * MB);
    u16 *KH = (u16 *)(w + 73 * MB);
    u16 *VT = (u16 *)(w + 77 * MB);
    u16 *attno = (u16 *)(w + 81 * MB);
    u16 *ch = (u16 *)(w + 85 * MB);
    u16 *cd = (u16 *)(w + 89 * MB);

    detect_k<<<dim3(1), dim3(256), 0, stream>>>((const u16 *)d_in[0], flag);
    CVT c;
    c.pre[0] = 0;
    for (int i = 0; i < 24; i++) {
        c.in[i] = d_in[i];
        c.pre[i + 1] = c.pre[i] + in_sizes[i];
    }
    long long total = c.pre[24];
    convert_k<<<dim3((unsigned)((total + 255) / 256)), dim3(256), 0, stream>>>(c, cv, flag, total);

    const u16 *src = cv + c.pre[0];
    const u16 *pos_emb = cv + c.pre[1];
    const u16 *w_qkv = cv + c.pre[2];
    const u16 *b_qkv = cv + c.pre[3];
    const u16 *w_o = cv + c.pre[4];
    const u16 *b_o = cv + c.pre[5];
    const u16 *w_pos = cv + c.pre[6];
    const u16 *u_bias = cv + c.pre[7];
    const u16 *v_bias = cv + c.pre[8];
    const u16 *ffm_w1 = cv + c.pre[9];
    const u16 *ffm_b1 = cv + c.pre[10];
    const u16 *ffm_w2 = cv + c.pre[11];
    const u16 *ffm_b2 = cv + c.pre[12];
    const u16 *ff_w1 = cv + c.pre[13];
    const u16 *ff_b1 = cv + c.pre[14];
    const u16 *ff_w2 = cv + c.pre[15];
    const u16 *ff_b2 = cv + c.pre[16];
    const u16 *pw1_w = cv + c.pre[17];
    const u16 *pw1_b = cv + c.pre[18];
    const u16 *dw_w = cv + c.pre[19];
    const u16 *dw_b = cv + c.pre[20];
    const u16 *pw2_w = cv + c.pre[21];
    const u16 *pw2_b = cv + c.pre[22];

    auto mk = [](const void *A, int lda, const void *B, int ldb, void *C, int ldc,
                 const void *bias, int M, int N, int K, int mode) {
        GP p;
        memset(&p, 0, sizeof(p));
        p.A = (const u16 *)A; p.B = (const u16 *)B; p.C = (u16 *)C; p.bias = (const u16 *)bias;
        p.M = M; p.N = N; p.K = K; p.lda = lda; p.ldb = ldb; p.ldc = ldc; p.mode = mode;
        p.qscale = 1.f;
        return p;
    };
    auto launch = [&](GP p) {
        dim3 g((p.N + 63) / 64, (p.M + 63) / 64, 1);
        gemm_nt<<<g, dim3(256), 0, stream>>>(p);
    };
    auto launch128 = [&](GP p) {
        dim3 g(p.N >> 7, p.M >> 7, 1);
        gemm_nt128<<<g, dim3(256), 0, stream>>>(p);
    };

    const int M = T_ * B_;  // 4096

    // ---- macaron FFN: x1 = src + W2 @ dswish(W1 @ src + b1) + b2
    { GP p = mk(src, E_, ffm_w1, E_, h1, DFF_, ffm_b1, M, DFF_, E_, 1); launch128(p); }
    { GP p = mk(h1, DFF_, ffm_w2, DFF_, nullptr, E_, ffm_b2, M, E_, DFF_, 2);
      p.resin = d_in[0]; p.resin_f32 = 1; p.xr = xr; p.xb = xb; launch(p); }

    // ---- attention projections (qkv epilogue writes QU/QV/KH/VT directly)
    { GP p = mk(xb, E_, w_qkv, E_, nullptr, 3 * E_, b_qkv, M, 3 * E_, E_, 4);
      p.qcols = E_; p.qscale = 0.125f;
      p.ub = u_bias; p.vb = v_bias; p.qu = QU; p.qv = QV; p.kh = KH; p.vt = VT;
      launch128(p); }
    // pos GEMM writes pph directly (mode 3, fused repack + zero pad row 2047)
    { GP p = mk(pos_emb, E_, w_pos, E_, pph, E_, nullptr, 2 * T_ - 1, E_, E_, 3); launch(p); }

    // ---- flash attention (no S materialization)
    {
        FK f;
        f.QU = QU; f.QV = QV; f.KH = KH; f.PPH = pph; f.VT = VT; f.attno = attno;
        flash_k<<<dim3(16, 32), dim3(256), 0, stream>>>(f);
    }

    // ---- out projection + residual -> x2
    { GP p = mk(attno, E_, w_o, E_, nullptr, E_, b_o, M, E_, E_, 2);
      p.resin = xr; p.resin_f32 = 1; p.xr = xr; p.xb = xb; launch(p); }

    // ---- conv module (pw1 + GLU fused)
    gemm_glu<<<dim3(8, 64), dim3(256), 0, stream>>>(xb, pw1_w, pw1_b, ch);
    dwconv_k<<<dim3(512), dim3(256), 0, stream>>>(ch, dw_w, dw_b, cd);
    { GP p = mk(cd, E_, pw2_w, E_, nullptr, E_, pw2_b, M, E_, E_, 2);
      p.resin = xr; p.resin_f32 = 1; p.xr = xr; p.xb = xb; launch(p); }

    // ---- second FFN
    { GP p = mk(xb, E_, ff_w1, E_, h1, DFF_, ff_b1, M, DFF_, E_, 1); launch128(p); }
    { GP p = mk(h1, DFF_, ff_w2, DFF_, nullptr, E_, ff_b2, M, E_, DFF_, 2);
      p.resin = xr; p.resin_f32 = 1; p.xr = xr; p.xb = nullptr; launch(p); }

    // ---- final BasicNorm -> d_out (FLOAT32)
    norm_k<<<dim3(M / 4), dim3(256), 0, stream>>>(xr, (const float *)d_in[23], (float *)d_out);
}

// Round 4
// 366.255 us; speedup vs baseline: 1.2329x; 1.1678x over previous
//
#include <hip/hip_runtime.h>
#include <string.h>

// Conformer encoder layer, MI355X gfx950 — ROUND 14.
// R13: 428 us. XCD swizzle verified (GEMM FETCH 17.6->8.7MB) but 4-buffer
// 64KB LDS halved occupancy (1 block/CU) -> gemm128 42->49us regression.
// Depth ladder on DFF shape: 1buf 64 / 2buf <=45 / 3buf <=42 / 4buf 49.
// Changes: GEMMs back to 3-buffer 48KB (proven best) + 512-thread 8-wave
// blocks (wave-tile 64x32 / 32x16): waves/CU 8->16 (2->4 per SIMD) to cover
// the per-step vmcnt+barrier stall with real TLP. Counted vmcnt(4/2/0),
// 2 loads/thread/stage. XCD swizzle kept on all GEMMs. flash_k, gemm_glu,
// helpers unchanged. Workspace: 93 MB.

#define T_ 1024
#define B_ 4
#define E_ 512
#define H_ 8
#define DFF_ 2048
#define KW_ 31

typedef unsigned short u16;
typedef unsigned int u32;
typedef __bf16 bf16x8 __attribute__((ext_vector_type(8)));
typedef float floatx4 __attribute__((ext_vector_type(4)));

__device__ __forceinline__ float b2f(u16 u) {
    return __uint_as_float(((u32)u) << 16);
}
__device__ __forceinline__ u16 f2b(float f) {
    u32 i = __float_as_uint(f);
    u32 r = (i + 0x7fffu + ((i >> 16) & 1u)) >> 16;  // RNE, finite inputs only
    return (u16)r;
}

__device__ __forceinline__ void glds16(const u16 *g, u16 *l) {
    __builtin_amdgcn_global_load_lds((const __attribute__((address_space(1))) void *)g,
                                     (__attribute__((address_space(3))) void *)l, 16, 0, 0);
}

// ---------------- diagnostic fill (f32 out) ---------------------------------------
__global__ __launch_bounds__(256) void fill_k(float *out, long long n, float val) {
    long long g = (long long)blockIdx.x * 256 + threadIdx.x;
    if (g < n) out[g] = val;
}

// ---------------- input dtype detect + convert ------------------------------------
__global__ __launch_bounds__(256) void detect_k(const u16 *src16, int *flag) {
    __shared__ int sh[256];
    int tid = threadIdx.x;
    int cnt = 0;
    for (int i = tid; i < 4096; i += 256) {
        u16 x = src16[2 * i];
        int e = (x >> 7) & 0xFF;
        cnt += (e == 0 || (e >= 0x70 && e <= 0x8F)) ? 1 : 0;
    }
    sh[tid] = cnt;
    __syncthreads();
    for (int s = 128; s; s >>= 1) {
        if (tid < s) sh[tid] += sh[tid + s];
        __syncthreads();
    }
    if (tid == 0) *flag = (sh[0] < 2048) ? 1 : 0;  // 1 = f32 inputs, 0 = bf16
}

struct CVT {
    const void *in[24];
    long long pre[25];
};

__global__ __launch_bounds__(256) void convert_k(CVT c, u16 *dst, const int *flag,
                                                 long long total) {
    long long g = (long long)blockIdx.x * 256 + threadIdx.x;
    if (g >= total) return;
    int s = 0;
#pragma unroll
    for (int i = 1; i < 25; i++) s += (g >= c.pre[i]) ? 1 : 0;
    long long l = g - c.pre[s];
    int f = *flag;
    u16 v = f ? f2b(((const float *)c.in[s])[l]) : ((const u16 *)c.in[s])[l];
    dst[g] = v;
}

// ---------------- generic NT GEMM: C(M,N) = A(M,K) @ B(N,K)^T ----------------------
struct GP {
    const u16 *A, *B;
    u16 *C;
    const u16 *bias;
    const void *resin;     // mode 2: residual input (bf16 or f32)
    float *xr;             // mode 2: f32 residual out
    u16 *xb;               // mode 2: bf16 copy out (may be null)
    const u16 *ub, *vb;    // mode 4: u/v biases
    u16 *qu, *qv, *kh, *vt;  // mode 4: fused qkv repack outputs
    int M, N, K, lda, ldb, ldc, mode, qcols, resin_f32;
    float qscale;
};

// 64x64 tile, BK=64, 512 threads / 8 waves (wave-tile 32x16), 3-buffer
// pipeline, counted vmcnt(4/2/0), XCD-swizzled grid, glds16 + XOR swizzle.
// modes: 0 bf16; 1 DoubleSwish; 2 residual; 3 pph repack.
__global__ __launch_bounds__(512) void gemm_nt(GP p) {
    __shared__ __align__(16) u16 As[3 * 4096];
    __shared__ __align__(16) u16 Bs[3 * 4096];
    const int tid = threadIdx.x;
    const int wv = tid >> 6, ln = tid & 63;
    const int l16 = ln & 15, quad = ln >> 4;
    const int wm = (wv >> 2) << 5;   // 0 / 32
    const int wn = (wv & 3) << 4;    // 0 / 16 / 32 / 48
    // XCD swizzle: grid.x*grid.y % 8 == 0 at every call site (bijective)
    const int gx = gridDim.x;
    const int nb = gx * gridDim.y;
    const int lid = blockIdx.y * gx + blockIdx.x;
    const int nid = (lid & 7) * (nb >> 3) + (lid >> 3);
    const int m0 = (nid / gx) << 6, n0 = (nid % gx) << 6;
    floatx4 zero = {0.f, 0.f, 0.f, 0.f};
    floatx4 acc[2];
    acc[0] = zero;
    acc[1] = zero;

    const int NT = p.K >> 6;  // BK=64; all call-site K >= 512 -> NT >= 8

    // stage: tile 64x64 = 4096 u16 = 512 threads x 8. 1 glds16 each for A,B.
    // Row-clamped A (no divergence, uniform vmcnt). Clamped rows masked at store.
    const int srow = tid >> 3;
    const int sg = ((tid & 7) ^ (srow & 7)) << 3;  // swizzled source granule
    int ra = m0 + srow;
    if (ra > p.M - 1) ra = p.M - 1;
    const u16 *Agp = p.A + (long long)ra * p.lda + sg;
    const u16 *Bgp = p.B + (long long)(n0 + srow) * p.ldb + sg;

    auto stage = [&](int bidx, int t) {  // 2 glds16 per thread
        const int k0 = t << 6;
        const int o = bidx << 12;  // 4096 u16 per buffer
        glds16(Agp + k0, As + o + tid * 8);
        glds16(Bgp + k0, Bs + o + tid * 8);
    };

    stage(0, 0);
    stage(1, 1);
    stage(2, 2);
    asm volatile("s_waitcnt vmcnt(4)" ::: "memory");  // buf0's 2 loads done
    __builtin_amdgcn_s_barrier();

    int cb = 0;  // t % 3
    for (int t = 0; t < NT; t++) {
        const int o = cb << 12;
#pragma unroll
        for (int kk = 0; kk < 2; kk++) {
            const int swz = ((((kk << 2) | quad) ^ (l16 & 7)) << 3);
            bf16x8 bfv = __builtin_bit_cast(bf16x8,
                *(const uint4 *)&Bs[o + ((wn + l16) << 6) + swz]);
#pragma unroll
            for (int mt = 0; mt < 2; mt++) {
                bf16x8 af = __builtin_bit_cast(bf16x8,
                    *(const uint4 *)&As[o + ((wm + (mt << 4) + l16) << 6) + swz]);
                acc[mt] = __builtin_amdgcn_mfma_f32_16x16x32_bf16(af, bfv, acc[mt], 0, 0, 0);
            }
        }
        if (t + 1 < NT) {
            __builtin_amdgcn_sched_barrier(0);   // reads of buf complete before barrier
            __builtin_amdgcn_s_barrier();        // all waves done reading buf t
            if (t + 3 < NT) {
                stage(cb, t + 3);                // re-stage retired buffer
                asm volatile("s_waitcnt vmcnt(4)" ::: "memory");  // buf t+1 done
            } else if (t + 2 < NT) {
                asm volatile("s_waitcnt vmcnt(2)" ::: "memory");
            } else {
                asm volatile("s_waitcnt vmcnt(0)" ::: "memory");
            }
            __builtin_amdgcn_s_barrier();        // buf t+1 visible everywhere
            __builtin_amdgcn_sched_barrier(0);   // no hoisting of next reads above this
        }
        cb = (cb == 2) ? 0 : cb + 1;
    }

#pragma unroll
    for (int mt = 0; mt < 2; mt++) {
#pragma unroll
        for (int r = 0; r < 4; r++) {
            int gr = m0 + wm + (mt << 4) + (quad << 2) + r;
            int gc = n0 + wn + l16;
            bool oob = gr >= p.M;
            if (oob && p.mode != 3) continue;
            float y = 0.f;
            if (!oob) {
                y = acc[mt][r];
                if (p.bias) y += b2f(p.bias[gc]);
                if (gc < p.qcols) y *= p.qscale;
            }
            if (p.mode == 3) {
                // fused repack_pos: C = pph, layout [(h*2048 + m)*64 + d]
                p.C[((gc >> 6) << 17) + (gr << 6) + (gc & 63)] = f2b(y);
            } else if (p.mode == 0) {
                p.C[(long long)gr * p.ldc + gc] = f2b(y);
            } else if (p.mode == 1) {
                float s = 1.f / (1.f + __expf(1.f - y));  // x*sigmoid(x-1)
                p.C[(long long)gr * p.ldc + gc] = f2b(y * s);
            } else {  // mode 2
                long long idx = (long long)gr * p.ldc + gc;
                float rv = p.resin_f32 ? ((const float *)p.resin)[idx]
                                       : b2f(((const u16 *)p.resin)[idx]);
                float o = rv + y;
                p.xr[idx] = o;
                if (p.xb) p.xb[idx] = f2b(o);
            }
        }
    }
}

// ---------------- 128x128 GEMM (M%128==0, N%128==0, K%32==0) -----------------------
// 512 threads / 8 waves (wave-tile 64x32, acc[4][2]), BK=32, 3-buffer,
// counted vmcnt(4/2/0), XCD swizzle, XOR-swizzled staging + reads.
__global__ __launch_bounds__(512) void gemm_nt128(GP p) {
    __shared__ __align__(16) u16 As[3 * 4096];
    __shared__ __align__(16) u16 Bs[3 * 4096];
    const int tid = threadIdx.x;
    const int wv = tid >> 6, ln = tid & 63;
    const int l16 = ln & 15, quad = ln >> 4;
    const int wm = (wv >> 2) << 6;   // 0 / 64
    const int wn = (wv & 3) << 5;    // 0 / 32 / 64 / 96
    // XCD swizzle (grid.x*grid.y % 8 == 0 at every call site)
    const int gx = gridDim.x;
    const int nb = gx * gridDim.y;
    const int lid = blockIdx.y * gx + blockIdx.x;
    const int nid = (lid & 7) * (nb >> 3) + (lid >> 3);
    const int m0 = (nid / gx) << 7, n0 = (nid % gx) << 7;
    // staging: tile 128x32 = 4096 u16 = 512 threads x 8. 1 glds16 each A,B.
    const int srow = tid >> 2;                       // 0..127
    const int sg = ((tid & 3) ^ ((tid >> 3) & 3)) << 3;  // swizzled granule
    const u16 *Agp = p.A + (long long)(m0 + srow) * p.lda + sg;
    const u16 *Bgp = p.B + (long long)(n0 + srow) * p.ldb + sg;
    floatx4 zero = {0.f, 0.f, 0.f, 0.f};
    floatx4 acc[4][2];
#pragma unroll
    for (int i = 0; i < 4; i++)
#pragma unroll
        for (int j = 0; j < 2; j++) acc[i][j] = zero;

    const int rswz = ((quad ^ ((l16 >> 1) & 3)) << 3);  // read-side swizzle
    const int NT = p.K >> 5;  // BK=32; K>=512 -> NT>=16

    auto stage = [&](int bidx, int t) {  // 2 glds16 per thread
        const int k0 = t << 5;
        const int o = bidx << 12;  // 4096 u16 per buffer
        glds16(Agp + k0, As + o + tid * 8);
        glds16(Bgp + k0, Bs + o + tid * 8);
    };

    stage(0, 0);
    stage(1, 1);
    stage(2, 2);
    asm volatile("s_waitcnt vmcnt(4)" ::: "memory");  // buf0's 2 loads done
    __builtin_amdgcn_s_barrier();

    int cb = 0;  // t % 3
    for (int t = 0; t < NT; t++) {
        const int o = cb << 12;
        bf16x8 av[4], bv[2];
#pragma unroll
        for (int mt = 0; mt < 4; mt++)
            av[mt] = __builtin_bit_cast(bf16x8,
                *(const uint4 *)&As[o + ((wm + (mt << 4) + l16) << 5) + rswz]);
#pragma unroll
        for (int nt = 0; nt < 2; nt++)
            bv[nt] = __builtin_bit_cast(bf16x8,
                *(const uint4 *)&Bs[o + ((wn + (nt << 4) + l16) << 5) + rswz]);
#pragma unroll
        for (int mt = 0; mt < 4; mt++)
#pragma unroll
            for (int nt = 0; nt < 2; nt++)
                acc[mt][nt] = __builtin_amdgcn_mfma_f32_16x16x32_bf16(av[mt], bv[nt],
                                                                      acc[mt][nt], 0, 0, 0);
        if (t + 1 < NT) {
            __builtin_amdgcn_sched_barrier(0);   // reads of buf complete before barrier
            __builtin_amdgcn_s_barrier();        // all waves done reading buf t
            if (t + 3 < NT) {
                stage(cb, t + 3);                // re-stage retired buffer
                asm volatile("s_waitcnt vmcnt(4)" ::: "memory");  // buf t+1 done
            } else if (t + 2 < NT) {
                asm volatile("s_waitcnt vmcnt(2)" ::: "memory");
            } else {
                asm volatile("s_waitcnt vmcnt(0)" ::: "memory");
            }
            __builtin_amdgcn_s_barrier();        // buf t+1 visible everywhere
            __builtin_amdgcn_sched_barrier(0);   // no hoisting of next reads above this
        }
        cb = (cb == 2) ? 0 : cb + 1;
    }

#pragma unroll
    for (int mt = 0; mt < 4; mt++)
#pragma unroll
        for (int nt = 0; nt < 2; nt++)
#pragma unroll
            for (int r = 0; r < 4; r++) {
                int gr = m0 + wm + (mt << 4) + (quad << 2) + r;
                int gc = n0 + wn + (nt << 4) + l16;
                float y = acc[mt][nt][r];
                if (p.bias) y += b2f(p.bias[gc]);
                if (gc < p.qcols) y *= p.qscale;
                if (p.mode == 0) {
                    p.C[(long long)gr * p.ldc + gc] = f2b(y);
                } else if (p.mode == 1) {
                    float s = 1.f / (1.f + __expf(1.f - y));
                    p.C[(long long)gr * p.ldc + gc] = f2b(y * s);
                } else if (p.mode == 4) {
                    // fused qkv repack: rows are (t,b) pairs, b fastest
                    int t = gr >> 2, b = gr & 3;
                    if (gc < E_) {  // Q -> QU/QV with u/v biases (y already scaled)
                        int z = b * 8 + (gc >> 6);
                        long long oq = ((long long)z << 16) + (t << 6) + (gc & 63);
                        p.qu[oq] = f2b(y + b2f(p.ub[gc]));
                        p.qv[oq] = f2b(y + b2f(p.vb[gc]));
                    } else if (gc < 2 * E_) {  // K -> KH [z][t][d]
                        int c = gc - E_;
                        int z = b * 8 + (c >> 6);
                        p.kh[((long long)z << 16) + (t << 6) + (c & 63)] = f2b(y);
                    } else {  // V -> VT [z*64+d][t] (transposed)
                        int c = gc - 2 * E_;
                        int z = b * 8 + (c >> 6);
                        p.vt[(long long)((z << 6) + (c & 63)) * T_ + t] = f2b(y);
                    }
                } else {  // mode 2
                    long long idx = (long long)gr * p.ldc + gc;
                    float rv = p.resin_f32 ? ((const float *)p.resin)[idx]
                                           : b2f(((const u16 *)p.resin)[idx]);
                    float o = rv + y;
                    p.xr[idx] = o;
                    if (p.xb) p.xb[idx] = f2b(o);
                }
            }
}

// ---------------- fused pw1 + GLU: ch(M,512) = GLU(A @ W^T + b) --------------------
// Block computes 64x64 of BOTH halves (a-cols n0.., g-cols 512+n0..) then
// writes ch = a * sigmoid(g) directly. 3-buffer pipeline, 6 loads/stage.
__global__ __launch_bounds__(256) void gemm_glu(const u16 *A, const u16 *W, const u16 *bias,
                                                u16 *ch) {
    __shared__ __align__(16) u16 As[3 * 4096];
    __shared__ __align__(16) u16 Ba[3 * 4096];
    __shared__ __align__(16) u16 Bg[3 * 4096];
    const int tid = threadIdx.x;
    const int wv = tid >> 6, ln = tid & 63;
    const int l16 = ln & 15, quad = ln >> 4;
    const int gx = gridDim.x;  // 8
    const int nb = gx * gridDim.y;  // 512
    const int lid = blockIdx.y * gx + blockIdx.x;
    const int nid = (lid & 7) * (nb >> 3) + (lid >> 3);
    const int m0 = (nid / gx) << 6, n0 = (nid % gx) << 6;
    floatx4 zero = {0.f, 0.f, 0.f, 0.f};
    floatx4 aa[4], ag[4];
#pragma unroll
    for (int i = 0; i < 4; i++) { aa[i] = zero; ag[i] = zero; }

    const int NT = 8;  // K=512, BK=64

    auto stage = [&](int bidx, int t) {  // 6 glds16 per thread
        const int k0 = t << 6;
        const int o = bidx << 12;
#pragma unroll
        for (int ps = 0; ps < 2; ps++) {
            int g = ps * 256 + tid;
            int row = g >> 3;
            int src = ((g & 7) ^ (row & 7)) << 3;
            glds16(A + ((m0 + row) << 9) + k0 + src, As + o + g * 8);
            glds16(W + ((n0 + row) << 9) + k0 + src, Ba + o + g * 8);
            glds16(W + ((E_ + n0 + row) << 9) + k0 + src, Bg + o + g * 8);
        }
    };

    stage(0, 0);
    stage(1, 1);
    stage(2, 2);
    asm volatile("s_waitcnt vmcnt(12)" ::: "memory");  // buf0's 6 loads done
    __builtin_amdgcn_s_barrier();

    int cb = 0;
    for (int t = 0; t < NT; t++) {
        const int o = cb << 12;
#pragma unroll
        for (int kk = 0; kk < 2; kk++) {
            const int swz = ((((kk << 2) | quad) ^ (l16 & 7)) << 3);
            bf16x8 af = __builtin_bit_cast(bf16x8,
                *(const uint4 *)&As[o + (((wv << 4) | l16) << 6) + swz]);
#pragma unroll
            for (int nt = 0; nt < 4; nt++) {
                bf16x8 bfa = __builtin_bit_cast(bf16x8,
                    *(const uint4 *)&Ba[o + (((nt << 4) | l16) << 6) + swz]);
                aa[nt] = __builtin_amdgcn_mfma_f32_16x16x32_bf16(af, bfa, aa[nt], 0, 0, 0);
                bf16x8 bfg = __builtin_bit_cast(bf16x8,
                    *(const uint4 *)&Bg[o + (((nt << 4) | l16) << 6) + swz]);
                ag[nt] = __builtin_amdgcn_mfma_f32_16x16x32_bf16(af, bfg, ag[nt], 0, 0, 0);
            }
        }
        if (t + 1 < NT) {
            __builtin_amdgcn_sched_barrier(0);
            __builtin_amdgcn_s_barrier();
            if (t + 3 < NT) {
                stage(cb, t + 3);
                asm volatile("s_waitcnt vmcnt(12)" ::: "memory");
            } else if (t + 2 < NT) {
                asm volatile("s_waitcnt vmcnt(6)" ::: "memory");
            } else {
                asm volatile("s_waitcnt vmcnt(0)" ::: "memory");
            }
            __builtin_amdgcn_s_barrier();
            __builtin_amdgcn_sched_barrier(0);
        }
        cb = (cb == 2) ? 0 : cb + 1;
    }

#pragma unroll
    for (int nt = 0; nt < 4; nt++) {
#pragma unroll
        for (int r = 0; r < 4; r++) {
            int gr = m0 + (wv << 4) + (quad << 2) + r;
            int gc = n0 + (nt << 4) + l16;
            float a = aa[nt][r] + b2f(bias[gc]);
            float g = ag[nt][r] + b2f(bias[E_ + gc]);
            ch[((long long)gr << 9) + gc] = f2b(a * (1.f / (1.f + __expf(-g))));
        }
    }
}

// ---------------- flash attention v3 (unchanged from R12) --------------------------
struct FK {
    const u16 *QU, *QV, *KH, *PPH, *VT;
    u16 *attno;
};

__global__ __launch_bounds__(256) void flash_k(FK p) {
    // per-buffer (16384 u16): Kh [0,4096) 64x64 | Vt [4096,8192) 64x64 |
    // Ph [8192,16384) 128x64. Pb at 32768: 64x72 (padded, per-lane stores).
    __shared__ __align__(16) u16 lds[2 * 16384 + 4608];  // 73 KB

    const int tid = threadIdx.x;
    const int wv = tid >> 6, ln = tid & 63;
    const int l16 = ln & 15, quad = ln >> 4;
    const int lid = blockIdx.y * 16 + blockIdx.x;
    const int nid = (lid & 7) * 64 + (lid >> 3);  // XCD-cluster swizzle (bijective)
    const int zg = nid >> 4;
    const int i0 = (nid & 15) << 6;
    const u16 *kh0 = p.KH + (long long)zg * 65536;
    const u16 *ph0 = p.PPH + (long long)(zg & 7) * 131072;
    const u16 *vt0 = p.VT + (long long)zg * 65536;
    u16 *Pb = lds + 32768;

    auto stage = [&](int buf, int jt) {  // 8 glds16 per thread
        const int j0 = jt << 6;
        const int m_start = 960 - i0 + j0;  // [0,1920]; +127 <= 2047 (pph pad row)
        u16 *Kh = lds + (buf << 14);
        u16 *Vt = Kh + 4096;
        u16 *Ph = Kh + 8192;
#pragma unroll
        for (int ps = 0; ps < 2; ps++) {
            int g = ps * 256 + tid;
            int row = g >> 3;
            int src = ((g & 7) ^ (row & 7)) << 3;
            glds16(kh0 + ((j0 + row) << 6) + src, Kh + g * 8);
            glds16(vt0 + (row << 10) + j0 + src, Vt + g * 8);
        }
#pragma unroll
        for (int ps = 0; ps < 4; ps++) {
            int g = ps * 256 + tid;
            int row = g >> 3;
            int src = ((g & 7) ^ (row & 7)) << 3;
            glds16(ph0 + ((m_start + row) << 6) + src, Ph + g * 8);
        }
    };

    // Q fragments from global into registers (A-layout: row l16, k quad*8+kk*32)
    const long long qoff = (long long)zg * 65536 + (long long)(i0 + (wv << 4) + l16) * 64 + (quad << 3);
    bf16x8 aqu[2], aqv[2];
#pragma unroll
    for (int kk = 0; kk < 2; kk++) {
        aqu[kk] = __builtin_bit_cast(bf16x8, *(const uint4 *)(p.QU + qoff + (kk << 5)));
        aqv[kk] = __builtin_bit_cast(bf16x8, *(const uint4 *)(p.QV + qoff + (kk << 5)));
    }

    stage(0, 0);
    asm volatile("s_waitcnt vmcnt(0)" ::: "memory");  // buf0 staged (+ Q loads done)
    __builtin_amdgcn_s_barrier();

    float lacc[4];
    floatx4 accO[4];
    floatx4 zero = {0.f, 0.f, 0.f, 0.f};
#pragma unroll
    for (int e = 0; e < 4; e++) lacc[e] = 0.f;
#pragma unroll
    for (int i = 0; i < 4; i++) accO[i] = zero;

    const int r16q = quad << 2;  // r16 base for this lane's quad

    for (int jt = 0; jt < 16; jt++) {
        if (jt + 1 < 16) stage((jt + 1) & 1, jt + 1);  // prefetch under compute
        __builtin_amdgcn_sched_barrier(0);             // issue loads first
        const int o = (jt & 1) << 14;
        const u16 *Kh = lds + o;
        const u16 *Vt = lds + o + 4096;
        const u16 *Ph = lds + o + 8192;

        // ---- score MFMAs
        floatx4 aS[4], aB[5];
#pragma unroll
        for (int i = 0; i < 4; i++) aS[i] = zero;
#pragma unroll
        for (int i = 0; i < 5; i++) aB[i] = zero;
        __builtin_amdgcn_s_setprio(1);
#pragma unroll
        for (int kk = 0; kk < 2; kk++) {
            const int swz = ((((kk << 2) | quad) ^ (l16 & 7)) << 3);
#pragma unroll
            for (int nt = 0; nt < 4; nt++) {
                bf16x8 bf = __builtin_bit_cast(bf16x8,
                    *(const uint4 *)&Kh[(((nt << 4) | l16) << 6) + swz]);
                aS[nt] = __builtin_amdgcn_mfma_f32_16x16x32_bf16(aqu[kk], bf, aS[nt], 0, 0, 0);
            }
#pragma unroll
            for (int rt = 0; rt < 5; rt++) {
                bf16x8 bf = __builtin_bit_cast(bf16x8,
                    *(const uint4 *)&Ph[((((rt + 3 - wv) << 4) | l16) << 6) + swz]);
                aB[rt] = __builtin_amdgcn_mfma_f32_16x16x32_bf16(aqv[kk], bf, aB[rt], 0, 0, 0);
            }
        }
        __builtin_amdgcn_s_setprio(0);

        // ---- assemble S = aS + shfl-remapped bd; no-max softmax; Pb write
#pragma unroll
        for (int e = 0; e < 4; e++) {
            const int r16 = r16q + e;
            const int t = l16 + 15 - r16;          // [0,30]
            const int srcl = (quad << 4) | (t & 15);
            const int carry = t >> 4;
            float ps = 0.f;
#pragma unroll
            for (int nt = 0; nt < 4; nt++) {
                float vlo = __shfl(aB[nt][e], srcl, 64);
                float vhi = __shfl(aB[nt + 1][e], srcl, 64);
                float bd = carry ? vhi : vlo;
                float pe = __expf(aS[nt][e] + bd);
                ps += pe;
                Pb[(((wv << 4) + r16) * 72) + (nt << 4) + l16] = f2b(pe);
            }
            lacc[e] += ps;
        }
        // Pb rows are wave-private: in-wave RAW handled by lgkmcnt, no barrier.

        // ---- PV MFMAs: accO += P(16x64) x V(64x64)
        __builtin_amdgcn_s_setprio(1);
#pragma unroll
        for (int kk = 0; kk < 2; kk++) {
            const int swz = ((((kk << 2) | quad) ^ (l16 & 7)) << 3);
            bf16x8 ap = __builtin_bit_cast(bf16x8,
                *(const uint4 *)&Pb[(((wv << 4) | l16) * 72) + (kk << 5) + (quad << 3)]);
#pragma unroll
            for (int nd = 0; nd < 4; nd++) {
                bf16x8 bv = __builtin_bit_cast(bf16x8,
                    *(const uint4 *)&Vt[(((nd << 4) | l16) << 6) + swz]);
                accO[nd] = __builtin_amdgcn_mfma_f32_16x16x32_bf16(ap, bv, accO[nd], 0, 0, 0);
            }
        }
        __builtin_amdgcn_s_setprio(0);

        if (jt + 1 < 16) {
            __builtin_amdgcn_sched_barrier(0);   // reads of buf jt done before barrier
            __builtin_amdgcn_s_barrier();        // all waves done reading buf jt
            asm volatile("s_waitcnt vmcnt(0)" ::: "memory");  // jt+1 loads landed
            __builtin_amdgcn_s_barrier();        // buf jt+1 visible everywhere
            __builtin_amdgcn_sched_barrier(0);
        }
    }

    // ---- epilogue: reduce l across quad (cols), then O/l -> attno (t, b, h*64+d)
    const int b = zg >> 3, h = zg & 7;
#pragma unroll
    for (int e = 0; e < 4; e++) {
#pragma unroll
        for (int msk = 1; msk < 16; msk <<= 1) lacc[e] += __shfl_xor(lacc[e], msk, 64);
        float inv = 1.f / lacc[e];
        int t = i0 + (wv << 4) + (quad << 2) + e;
#pragma unroll
        for (int nd = 0; nd < 4; nd++) {
            int d = (nd << 4) + l16;
            p.attno[(long long)(t * B_ + b) * E_ + h * 64 + d] = f2b(accO[nd][e] * inv);
        }
    }
}

// ---------------- small helper kernels -------------------------------------------

// depthwise conv — register sliding window. Thread = (b, channel-pair) x 8 t's.
__global__ __launch_bounds__(256) void dwconv_k(const u16 *ch, const u16 *w, const u16 *bias,
                                                u16 *cd) {
    const int cp = threadIdx.x;
    const int b = blockIdx.x >> 7;
    const int t0 = (blockIdx.x & 127) << 3;
    const int c0 = cp << 1;
    float in0[38], in1[38];
#pragma unroll
    for (int j = 0; j < 38; j++) {
        int tt = t0 - 15 + j;
        u32 v = 0;
        if (tt >= 0 && tt < T_) v = *(const u32 *)&ch[tt * 2048 + b * 512 + c0];
        in0[j] = b2f((u16)(v & 0xffff));
        in1[j] = b2f((u16)(v >> 16));
    }
    float w0[KW_], w1[KW_];
#pragma unroll
    for (int kk = 0; kk < KW_; kk++) {
        w0[kk] = b2f(w[c0 * KW_ + kk]);
        w1[kk] = b2f(w[c0 * KW_ + KW_ + kk]);
    }
    float bi0 = b2f(bias[c0]), bi1 = b2f(bias[c0 + 1]);
#pragma unroll
    for (int t = 0; t < 8; t++) {
        float a0 = bi0, a1 = bi1;
#pragma unroll
        for (int kk = 0; kk < KW_; kk++) {
            a0 += in0[t + kk] * w0[kk];
            a1 += in1[t + kk] * w1[kk];
        }
        float s0 = 1.f / (1.f + __expf(1.f - a0));
        float s1 = 1.f / (1.f + __expf(1.f - a1));
        u32 o = (u32)f2b(a0 * s0) | ((u32)f2b(a1 * s1) << 16);
        *(u32 *)&cd[(t0 + t) * 2048 + b * 512 + c0] = o;
    }
}

// BasicNorm -> FLOAT32 output. One wave per row.
__global__ __launch_bounds__(256) void norm_k(const float *xr, const float *epsp, float *out) {
    int wv = threadIdx.x >> 6, ln = threadIdx.x & 63;
    long long row = blockIdx.x * 4 + wv;
    const float *x = xr + row * E_;
    float vals[8], ss = 0.f;
#pragma unroll
    for (int i = 0; i < 8; i++) {
        vals[i] = x[ln + (i << 6)];
        ss += vals[i] * vals[i];
    }
#pragma unroll
    for (int m = 32; m; m >>= 1) ss += __shfl_xor(ss, m, 64);
    float sc = rsqrtf(ss * (1.f / (float)E_) + __expf(epsp[0]));
    float *o = out + row * E_;
#pragma unroll
    for (int i = 0; i < 8; i++) o[ln + (i << 6)] = vals[i] * sc;
}

// ---------------- host ------------------------------------------------------------

extern "C" void kernel_launch(void *const *d_in, const int *in_sizes, int n_in,
                              void *d_out, int out_size, void *d_ws, size_t ws_size,
                              hipStream_t stream) {
    const size_t MB = (size_t)1 << 20;
    static const long long EXPECT[24] = {
        2097152, 1048064, 786432, 1536, 262144, 512, 262144, 512, 512,
        1048576, 2048, 1048576, 512, 1048576, 2048, 1048576, 512,
        524288, 1024, 15872, 512, 262144, 512, 1};
    const size_t NEED = 93 * MB;

    float code = 0.f;
    if (n_in != 24) {
        code = 1000.f + (float)n_in;
    } else {
        for (int i = 0; i < 24; i++) {
            if ((long long)in_sizes[i] != EXPECT[i]) { code = 2000.f + 64.f * i; break; }
        }
    }
    if (code == 0.f && out_size != 2097152) code = 3000.f;
    if (code == 0.f && ws_size < NEED) code = 5000.f + (float)(ws_size / MB);
    if (code != 0.f) {
        long long n = (long long)out_size;
        fill_k<<<dim3((unsigned)((n + 255) / 256)), dim3(256), 0, stream>>>((float *)d_out, n, code);
        return;
    }

    char *w = (char *)d_ws;
    int *flag = (int *)(w + 0);
    u16 *cv = (u16 *)(w + 1 * MB);
    float *xr = (float *)(w + 21 * MB);
    u16 *xb = (u16 *)(w + 29 * MB);
    u16 *h1 = (u16 *)(w + 33 * MB);
    u16 *pph = (u16 *)(w + 63 * MB);
    u16 *QU = (u16 *)(w + 65 * MB);
    u16 *QV = (u16 *)(w + 69 * MB);
    u16 *KH = (u16 *)(w + 73 * MB);
    u16 *VT = (u16 *)(w + 77 * MB);
    u16 *attno = (u16 *)(w + 81 * MB);
    u16 *ch = (u16 *)(w + 85 * MB);
    u16 *cd = (u16 *)(w + 89 * MB);

    detect_k<<<dim3(1), dim3(256), 0, stream>>>((const u16 *)d_in[0], flag);
    CVT c;
    c.pre[0] = 0;
    for (int i = 0; i < 24; i++) {
        c.in[i] = d_in[i];
        c.pre[i + 1] = c.pre[i] + in_sizes[i];
    }
    long long total = c.pre[24];
    convert_k<<<dim3((unsigned)((total + 255) / 256)), dim3(256), 0, stream>>>(c, cv, flag, total);

    const u16 *src = cv + c.pre[0];
    const u16 *pos_emb = cv + c.pre[1];
    const u16 *w_qkv = cv + c.pre[2];
    const u16 *b_qkv = cv + c.pre[3];
    const u16 *w_o = cv + c.pre[4];
    const u16 *b_o = cv + c.pre[5];
    const u16 *w_pos = cv + c.pre[6];
    const u16 *u_bias = cv + c.pre[7];
    const u16 *v_bias = cv + c.pre[8];
    const u16 *ffm_w1 = cv + c.pre[9];
    const u16 *ffm_b1 = cv + c.pre[10];
    const u16 *ffm_w2 = cv + c.pre[11];
    const u16 *ffm_b2 = cv + c.pre[12];
    const u16 *ff_w1 = cv + c.pre[13];
    const u16 *ff_b1 = cv + c.pre[14];
    const u16 *ff_w2 = cv + c.pre[15];
    const u16 *ff_b2 = cv + c.pre[16];
    const u16 *pw1_w = cv + c.pre[17];
    const u16 *pw1_b = cv + c.pre[18];
    const u16 *dw_w = cv + c.pre[19];
    const u16 *dw_b = cv + c.pre[20];
    const u16 *pw2_w = cv + c.pre[21];
    const u16 *pw2_b = cv + c.pre[22];

    auto mk = [](const void *A, int lda, const void *B, int ldb, void *C, int ldc,
                 const void *bias, int M, int N, int K, int mode) {
        GP p;
        memset(&p, 0, sizeof(p));
        p.A = (const u16 *)A; p.B = (const u16 *)B; p.C = (u16 *)C; p.bias = (const u16 *)bias;
        p.M = M; p.N = N; p.K = K; p.lda = lda; p.ldb = ldb; p.ldc = ldc; p.mode = mode;
        p.qscale = 1.f;
        return p;
    };
    auto launch = [&](GP p) {
        dim3 g((p.N + 63) / 64, (p.M + 63) / 64, 1);
        gemm_nt<<<g, dim3(512), 0, stream>>>(p);
    };
    auto launch128 = [&](GP p) {
        dim3 g(p.N >> 7, p.M >> 7, 1);
        gemm_nt128<<<g, dim3(512), 0, stream>>>(p);
    };

    const int M = T_ * B_;  // 4096

    // ---- macaron FFN: x1 = src + W2 @ dswish(W1 @ src + b1) + b2
    { GP p = mk(src, E_, ffm_w1, E_, h1, DFF_, ffm_b1, M, DFF_, E_, 1); launch128(p); }
    { GP p = mk(h1, DFF_, ffm_w2, DFF_, nullptr, E_, ffm_b2, M, E_, DFF_, 2);
      p.resin = d_in[0]; p.resin_f32 = 1; p.xr = xr; p.xb = xb; launch(p); }

    // ---- attention projections (qkv epilogue writes QU/QV/KH/VT directly)
    { GP p = mk(xb, E_, w_qkv, E_, nullptr, 3 * E_, b_qkv, M, 3 * E_, E_, 4);
      p.qcols = E_; p.qscale = 0.125f;
      p.ub = u_bias; p.vb = v_bias; p.qu = QU; p.qv = QV; p.kh = KH; p.vt = VT;
      launch128(p); }
    // pos GEMM writes pph directly (mode 3, fused repack + zero pad row 2047)
    { GP p = mk(pos_emb, E_, w_pos, E_, pph, E_, nullptr, 2 * T_ - 1, E_, E_, 3); launch(p); }

    // ---- flash attention (no S materialization)
    {
        FK f;
        f.QU = QU; f.QV = QV; f.KH = KH; f.PPH = pph; f.VT = VT; f.attno = attno;
        flash_k<<<dim3(16, 32), dim3(256), 0, stream>>>(f);
    }

    // ---- out projection + residual -> x2
    { GP p = mk(attno, E_, w_o, E_, nullptr, E_, b_o, M, E_, E_, 2);
      p.resin = xr; p.resin_f32 = 1; p.xr = xr; p.xb = xb; launch(p); }

    // ---- conv module (pw1 + GLU fused)
    gemm_glu<<<dim3(8, 64), dim3(256), 0, stream>>>(xb, pw1_w, pw1_b, ch);
    dwconv_k<<<dim3(512), dim3(256), 0, stream>>>(ch, dw_w, dw_b, cd);
    { GP p = mk(cd, E_, pw2_w, E_, nullptr, E_, pw2_b, M, E_, E_, 2);
      p.resin = xr; p.resin_f32 = 1; p.xr = xr; p.xb = xb; launch(p); }

    // ---- second FFN
    { GP p = mk(xb, E_, ff_w1, E_, h1, DFF_, ff_b1, M, DFF_, E_, 1); launch128(p); }
    { GP p = mk(h1, DFF_, ff_w2, DFF_, nullptr, E_, ff_b2, M, E_, DFF_, 2);
      p.resin = xr; p.resin_f32 = 1; p.xr = xr; p.xb = nullptr; launch(p); }

    // ---- final BasicNorm -> d_out (FLOAT32)
    norm_k<<<dim3(M / 4), dim3(256), 0, stream>>>(xr, (const float *)d_in[23], (float *)d_out);
}